// Round 9
// baseline (668.812 us; speedup 1.0000x reference)
//
#include <hip/hip_runtime.h>

typedef unsigned short u16;
typedef __attribute__((ext_vector_type(4))) unsigned short u16x4;
typedef __attribute__((ext_vector_type(8))) unsigned short u16x8;
typedef __attribute__((ext_vector_type(8))) __bf16 bf16x8;
typedef __attribute__((ext_vector_type(4))) float f32x4;

#define DEV __device__ __forceinline__

DEV float b2f(u16 u){ union{ unsigned int i; float f; } x; x.i = ((unsigned int)u) << 16; return x.f; }
DEV u16 f2b(float f){ unsigned int x = __float_as_uint(f); return (u16)((x + 0x7fffu + ((x >> 16) & 1u)) >> 16); }
DEV u16 f2bc(float f){ __bf16 h = (__bf16)f; return *(u16*)&h; }   // native RNE cvt (1 VALU op)

// T1: XCD-aware block remap. Blocks sharing `bh` (same K/V/Q panels) are clustered on
// one XCD so its private L2 holds the panel once, instead of all 8 XCDs streaming it
// from HBM independently. R14 measured: FETCH 99MB -> 16.7MB (6x), passB 84 -> 78us.
// Bijective when total%8==0 and nbh%8==0 (all our grids satisfy this).
DEV void xcd_remap(int nx, int nbh, int nz, int& x, int& bh, int& z){
  int hwid = blockIdx.x + nx*(blockIdx.y + nbh*blockIdx.z);
  int xcd = hwid & 7, slot = hwid >> 3;
  int bhper = nbh >> 3;
  int pg = nx*nz;
  bh = xcd*bhper + slot/pg;
  int rem = slot % pg;
  z = rem / nx;
  x = rem % nx;
}

// ---------------------------------------------------------------- block reduce (256 thr)
DEV void block_red2(float& s, float& q){
#pragma unroll
  for (int off = 32; off; off >>= 1){ s += __shfl_down(s, off); q += __shfl_down(q, off); }
  __shared__ float sh1[4], sh2[4];
  int lane = threadIdx.x & 63, w = threadIdx.x >> 6;
  if (lane == 0){ sh1[w] = s; sh2[w] = q; }
  __syncthreads();
  s = sh1[0] + sh1[1] + sh1[2] + sh1[3];
  q = sh2[0] + sh2[1] + sh2[2] + sh2[3];
}

// ---------------------------------------------------------------- GEMM  C = A[M,K] * B[N,K]^T
// m97 recipe: async global->LDS (width 16), unpadded lane-contiguous LDS tiles.
// (no setprio here: m190 measured setprio NULL/negative on barrier-lockstep GEMM)
template<int WM, int WN, bool OUTB>
__global__ __launch_bounds__(WM*WN*64) void gemm_bt(
    const u16* __restrict__ A, const u16* __restrict__ Bm, void* __restrict__ Cp,
    int K, int lda, int ldb, int ldc, int Hh,
    long aob, long aoh, long bob, long boh, long cob, long coh)
{
  constexpr int BM = WM*64, BN = WN*64, BK = 64, NW = WM*WN;
  __shared__ u16 At[BM*64];
  __shared__ u16 Bt[BN*64];
  int z = blockIdx.z, b_ = z / Hh, h_ = z % Hh;
  const u16* Ab = A + (long)b_*aob + (long)h_*aoh;
  const u16* Bb = Bm + (long)b_*bob + (long)h_*boh;
  long cbase = (long)b_*cob + (long)h_*coh;
  int m0 = blockIdx.y * BM, n0 = blockIdx.x * BN;
  int tid = threadIdx.x, lane = tid & 63, wv = tid >> 6;
  int wm = wv / WN, wn = wv % WN;
  f32x4 acc[4][4];
  f32x4 z4 = {0.f, 0.f, 0.f, 0.f};
#pragma unroll
  for (int a = 0; a < 4; a++)
#pragma unroll
    for (int b = 0; b < 4; b++) acc[a][b] = z4;
  int lr = lane & 15, lk8 = (lane >> 4) * 8;
  int rq = lane >> 3, cq = (lane & 7) << 3;      // lane -> (row-in-8, col-16B) of one inst
  for (int k0 = 0; k0 < K; k0 += BK){
    __syncthreads();                             // prev MFMA reads done before overwrite
#pragma unroll
    for (int q = wv; q < BM/8; q += NW){
      const u16* g = &Ab[(long)(m0 + q*8 + rq)*lda + k0 + cq];
      __builtin_amdgcn_global_load_lds((const __attribute__((address_space(1))) void*)g,
          (__attribute__((address_space(3))) void*)&At[q*512], 16, 0, 0);
    }
#pragma unroll
    for (int q = wv; q < BN/8; q += NW){
      const u16* g = &Bb[(long)(n0 + q*8 + rq)*ldb + k0 + cq];
      __builtin_amdgcn_global_load_lds((const __attribute__((address_space(1))) void*)g,
          (__attribute__((address_space(3))) void*)&Bt[q*512], 16, 0, 0);
    }
    __syncthreads();                             // drains vmcnt (loads landed in LDS)
#pragma unroll
    for (int kk = 0; kk < BK; kk += 32){
      bf16x8 af[4], bfr[4];
#pragma unroll
      for (int mi = 0; mi < 4; mi++) af[mi]  = *(bf16x8*)&At[(wm*64 + mi*16 + lr)*64 + kk + lk8];
#pragma unroll
      for (int ni = 0; ni < 4; ni++) bfr[ni] = *(bf16x8*)&Bt[(wn*64 + ni*16 + lr)*64 + kk + lk8];
#pragma unroll
      for (int mi = 0; mi < 4; mi++)
#pragma unroll
        for (int ni = 0; ni < 4; ni++)
          acc[mi][ni] = __builtin_amdgcn_mfma_f32_16x16x32_bf16(af[mi], bfr[ni], acc[mi][ni], 0, 0, 0);
    }
  }
  int orow = (lane >> 4) * 4, ocol = lane & 15;
#pragma unroll
  for (int mi = 0; mi < 4; mi++)
#pragma unroll
    for (int ni = 0; ni < 4; ni++){
      int row = m0 + wm*64 + mi*16 + orow;
      int col = n0 + wn*64 + ni*16 + ocol;
      long cidx = cbase + (long)row*ldc + col;
#pragma unroll
      for (int r = 0; r < 4; r++){
        float vv = acc[mi][ni][r];
        if (OUTB) ((u16*)Cp)[cidx + (long)r*ldc] = f2b(vv);
        else      ((float*)Cp)[cidx + (long)r*ldc] = vv;
      }
    }
}

// ---------------------------------------------------------------- fused attention
// Pass A: per (b,h,j-tile of 64): m_j, 1/Z_j over all i (masked). 4 waves x 16 j-rows.
// R9 proven form: batched register staging + 1-tile-ahead prefetch, reg-resident K.
// R14: + T1 XCD remap.  R15: + T5 setprio around the QK^T MFMA cluster (m191: +4-7%
// attn when resident waves are at different phases — true here: independent blocks,
// 3-4 blocks/CU, stage/compute phases unaligned).
template<int KD, bool MASK>
__global__ __launch_bounds__(256) void attn_passA(
    const u16* __restrict__ Kp, const u16* __restrict__ Qp, float* __restrict__ mz,
    int J, int kld, int qld,
    long kob, long koh, long qob, long qoh, int H, float scale, int mztot)
{
  constexpr int KP = KD + 8;
  constexpr int RCH = KD / 8;
  constexpr int QREG = KD / 16;            // u16x8 regs per thread for the 128-row Q tile
  __shared__ u16 Qt[128*KP];
  int bx, bh, bz;
  xcd_remap(gridDim.x, gridDim.y, gridDim.z, bx, bh, bz);
  int b = bh / H, h = bh % H;
  const u16* Kb = Kp + (long)b*kob + (long)h*koh;
  const u16* Qb = Qp + (long)b*qob + (long)h*qoh;
  int j0 = bx * 64;
  int tid = threadIdx.x, lane = tid & 63, w = tid >> 6;
  int lr = lane & 15, lk8 = (lane >> 4) * 8;
  bf16x8 ak[KD/32];
  {
    const u16* kr = &Kb[(long)(j0 + w*16 + lr)*kld];
#pragma unroll
    for (int kk = 0; kk < KD/32; kk++) ak[kk] = *(const bf16x8*)&kr[kk*32 + lk8];
  }
  float m_run[4], z_run[4];
#pragma unroll
  for (int r = 0; r < 4; r++){ m_run[r] = -3.0e38f; z_run[r] = 0.f; }
  f32x4 zz = {0.f,0.f,0.f,0.f};
  int itLo = 0;
  if (MASK){ int tt = j0 - 1151; itLo = tt > 0 ? (tt + 127)/128 : 0; }
  u16x8 qreg[QREG];
#pragma unroll
  for (int qq = 0; qq < QREG; qq++){
    int idx = tid + qq*256; int r = idx / RCH, c = (idx % RCH) * 8;
    qreg[qq] = *(const u16x8*)&Qb[(long)(itLo*128 + r)*qld + c];
  }
  for (int it = itLo; it < 8; it++){
    __syncthreads();                       // prior Qt reads done before overwrite
#pragma unroll
    for (int qq = 0; qq < QREG; qq++){
      int idx = tid + qq*256; int r = idx / RCH, c = (idx % RCH) * 8;
      *(u16x8*)&Qt[r*KP + c] = qreg[qq];
    }
    if (it + 1 < 8){
#pragma unroll
      for (int qq = 0; qq < QREG; qq++){
        int idx = tid + qq*256; int r = idx / RCH, c = (idx % RCH) * 8;
        qreg[qq] = *(const u16x8*)&Qb[(long)((it+1)*128 + r)*qld + c];
      }
    }
    __syncthreads();                       // Qt ready
    f32x4 acc[8];
#pragma unroll
    for (int ni = 0; ni < 8; ni++) acc[ni] = zz;
    __builtin_amdgcn_s_setprio(1);         // T5: favor this wave's compute phase
#pragma unroll
    for (int kk = 0; kk < KD; kk += 32){
      bf16x8 bq[8];
#pragma unroll
      for (int ni = 0; ni < 8; ni++) bq[ni] = *(bf16x8*)&Qt[(ni*16 + lr)*KP + kk + lk8];
#pragma unroll
      for (int ni = 0; ni < 8; ni++)
        acc[ni] = __builtin_amdgcn_mfma_f32_16x16x32_bf16(ak[kk/32], bq[ni], acc[ni], 0, 0, 0);
    }
    __builtin_amdgcn_s_setprio(0);
#pragma unroll
    for (int r = 0; r < 4; r++){
      int jg = j0 + w*16 + ((lane >> 4) << 2) + r;
      float sv[8]; float tm = -3.0e38f;
#pragma unroll
      for (int ni = 0; ni < 8; ni++){
        int ig = it*128 + ni*16 + (lane & 15);
        float s = acc[ni][r] * scale;
        bool val = (!MASK) || (ig >= jg - 1024);
        sv[ni] = val ? s : -3.0e38f;
        tm = fmaxf(tm, sv[ni]);
      }
#pragma unroll
      for (int off = 1; off < 16; off <<= 1) tm = fmaxf(tm, __shfl_xor(tm, off));
      float mn = fmaxf(m_run[r], tm);
      float zt = 0.f;
#pragma unroll
      for (int ni = 0; ni < 8; ni++)
        zt += (sv[ni] > -1.0e37f) ? __expf(sv[ni] - mn) : 0.f;
#pragma unroll
      for (int off = 1; off < 16; off <<= 1) zt += __shfl_xor(zt, off);
      z_run[r] = z_run[r] * __expf(m_run[r] - mn) + zt;
      m_run[r] = mn;
    }
  }
  if ((lane & 15) == 0){
#pragma unroll
    for (int r = 0; r < 4; r++){
      int jg = j0 + w*16 + ((lane >> 4) << 2) + r;
      mz[(long)bh*J + jg] = m_run[r];
      mz[(long)mztot + (long)bh*J + jg] = 1.f / z_run[r];
    }
  }
}

// Pass B: per (b,h,i-tile of 64, j-half). R9 proven body (KVBLK=128, batched register
// staging + 1-tile prefetch, reg-resident Q, LDS-staged K/V with K/P alias).
// R14: + T1 XCD remap; native (__bf16) RNE P-write.  R15: + T5 setprio around the
// QK^T and PV MFMA clusters.
template<int KD, bool MASK>
__global__ __launch_bounds__(256) void attn_passB(
    const u16* __restrict__ Kp, const u16* __restrict__ Qp, const u16* __restrict__ Vtp,
    const float* __restrict__ mz, float* __restrict__ Op,
    int J, int kld, int qld, int vld, int oldd,
    long kob, long koh, long qob, long qoh, long vob, long voh, long oob, long ooh,
    int H, float scale, int mztot, int jtHalf, long opstride)
{
  constexpr int KP = KD + 8, PSTR = 140, VSTR = 136;
  constexpr int RCH = KD / 8;
  constexpr int KREG = KD / 16;            // u16x8 regs per thread for the 128-row K tile
  __shared__ u16 PK[128*KP];       // K tile (128 x KP) ; aliased by P tile (64 x PSTR)
  __shared__ u16 Vtt[64*VSTR];
  u16* Kt = PK;
  u16* Pt = PK;
  int bx, bh, jh;
  xcd_remap(gridDim.x, gridDim.y, gridDim.z, bx, bh, jh);
  int b = bh / H, h = bh % H;
  const u16* Kb = Kp + (long)b*kob + (long)h*koh;
  const u16* Qb = Qp + (long)b*qob + (long)h*qoh;
  const u16* Vb = Vtp + (long)b*vob + (long)h*voh;
  float* Ob = Op + (long)jh*opstride + (long)b*oob + (long)h*ooh;
  const float* mzm = mz + (long)bh*J;
  const float* mzz = mz + (long)mztot + (long)bh*J;
  int i0 = bx * 64;
  int tid = threadIdx.x, lane = tid & 63, w = tid >> 6;
  int lr = lane & 15, lk8 = (lane >> 4) * 8;
  // Q fragment in registers: wave's own 16 i-rows, reused across all j-tiles
  bf16x8 aq[KD/32];
  {
    const u16* qr = &Qb[(long)(i0 + w*16 + lr)*qld];
#pragma unroll
    for (int kk = 0; kk < KD/32; kk++) aq[kk] = *(const bf16x8*)&qr[kk*32 + lk8];
  }
  f32x4 acc_o[4];
  f32x4 zz = {0.f,0.f,0.f,0.f};
#pragma unroll
  for (int nd = 0; nd < 4; nd++) acc_o[nd] = zz;
  int lo = jh * jtHalf, hi = lo + jtHalf;
  if (MASK){ int lim = (i0 + 1087)/128 + 1; hi = hi < lim ? hi : lim; }
  if (lo < hi){
    u16x8 kreg[KREG];
    u16x8 vreg[4];
#pragma unroll
    for (int qq = 0; qq < KREG; qq++){
      int idx = tid + qq*256; int r = idx / RCH, c = (idx % RCH) * 8;
      kreg[qq] = *(const u16x8*)&Kb[(long)(lo*128 + r)*kld + c];
    }
#pragma unroll
    for (int qq = 0; qq < 4; qq++){
      int idx = tid + qq*256; int r = idx >> 4, c = (idx & 15) << 3;
      vreg[qq] = *(const u16x8*)&Vb[(long)r*vld + lo*128 + c];
    }
    for (int jt = lo; jt < hi; jt++){
      __syncthreads();                     // prior P/Vt reads done before restage
#pragma unroll
      for (int qq = 0; qq < KREG; qq++){
        int idx = tid + qq*256; int r = idx / RCH, c = (idx % RCH) * 8;
        *(u16x8*)&Kt[r*KP + c] = kreg[qq];
      }
#pragma unroll
      for (int qq = 0; qq < 4; qq++){
        int idx = tid + qq*256; int r = idx >> 4, c = (idx & 15) << 3;
        *(u16x8*)&Vtt[r*VSTR + c] = vreg[qq];
      }
      if (jt + 1 < hi){                    // prefetch next tile during this tile's compute
#pragma unroll
        for (int qq = 0; qq < KREG; qq++){
          int idx = tid + qq*256; int r = idx / RCH, c = (idx % RCH) * 8;
          kreg[qq] = *(const u16x8*)&Kb[(long)((jt+1)*128 + r)*kld + c];
        }
#pragma unroll
        for (int qq = 0; qq < 4; qq++){
          int idx = tid + qq*256; int r = idx >> 4, c = (idx & 15) << 3;
          vreg[qq] = *(const u16x8*)&Vb[(long)r*vld + (jt+1)*128 + c];
        }
      }
      __syncthreads();                     // K/V LDS ready
      float mjv[8], zjv[8];
#pragma unroll
      for (int ni = 0; ni < 8; ni++){      // issue before MFMA: latency hides under QK^T
        int jg = jt*128 + ni*16 + (lane & 15);
        mjv[ni] = mzm[jg]; zjv[ni] = mzz[jg];
      }
      // S tile: A = Q regs (own wave's 16 i-rows), B = K (128 j)
      f32x4 acc[8];
#pragma unroll
      for (int ni = 0; ni < 8; ni++) acc[ni] = zz;
      __builtin_amdgcn_s_setprio(1);       // T5
#pragma unroll
      for (int kk = 0; kk < KD; kk += 32){
        bf16x8 bk[8];
#pragma unroll
        for (int ni = 0; ni < 8; ni++) bk[ni] = *(bf16x8*)&Kt[(ni*16 + lr)*KP + kk + lk8];
#pragma unroll
        for (int ni = 0; ni < 8; ni++)
          acc[ni] = __builtin_amdgcn_mfma_f32_16x16x32_bf16(aq[kk/32], bk[ni], acc[ni], 0, 0, 0);
      }
      __builtin_amdgcn_s_setprio(0);
      __syncthreads();                     // K reads done before P overwrite (alias)
#pragma unroll
      for (int ni = 0; ni < 8; ni++){
        int jg = jt*128 + ni*16 + (lane & 15);
#pragma unroll
        for (int r = 0; r < 4; r++){
          int ig = i0 + w*16 + ((lane >> 4) << 2) + r;
          bool val = (!MASK) || (ig >= jg - 1024);
          float p = val ? __expf(acc[ni][r] * scale - mjv[ni]) * zjv[ni] : 0.f;
          Pt[(w*16 + ((lane >> 4) << 2) + r)*PSTR + ni*16 + (lane & 15)] = f2bc(p);
        }
      }
      // no barrier: P write->read is within-wave (own 16 rows), DS pipe is in-order
      // PV: A = P (own wave's 16 i-rows), B = Vt (64 d-rows)
      __builtin_amdgcn_s_setprio(1);       // T5
#pragma unroll
      for (int kk = 0; kk < 128; kk += 32){
        bf16x8 pa, vb[4];
        pa = *(bf16x8*)&Pt[(w*16 + lr)*PSTR + kk + lk8];
#pragma unroll
        for (int nd = 0; nd < 4; nd++) vb[nd] = *(bf16x8*)&Vtt[(nd*16 + lr)*VSTR + kk + lk8];
#pragma unroll
        for (int nd = 0; nd < 4; nd++)
          acc_o[nd] = __builtin_amdgcn_mfma_f32_16x16x32_bf16(pa, vb[nd], acc_o[nd], 0, 0, 0);
      }
      __builtin_amdgcn_s_setprio(0);
    }
  }
#pragma unroll
  for (int nd = 0; nd < 4; nd++)
#pragma unroll
    for (int r = 0; r < 4; r++){
      int ig = i0 + w*16 + ((lane >> 4) << 2) + r;
      int d = nd*16 + (lane & 15);
      Ob[(long)ig*oldd + d] = acc_o[nd][r];
    }
}

// ---------------------------------------------------------------- o = bf16(part0 + part1)
__global__ __launch_bounds__(256) void combine_o(const float* __restrict__ p, u16* __restrict__ o)
{
  const long PS = 2097152;
  long i = ((long)blockIdx.x*256 + threadIdx.x) * 4;
  const float* a = &p[i];
  const float* b = &p[i + PS];
  u16x4 r;
#pragma unroll
  for (int e = 0; e < 4; e++) r[e] = f2b(a[e] + b[e]);
  *(u16x4*)&o[i] = r;
}

// ---------------------------------------------------------------- bf16 transpose dst[c,r]=src[r,c]
__global__ __launch_bounds__(256) void transpose_k(
    const u16* __restrict__ src, u16* __restrict__ dst,
    int lds_, int ldd, int Hh, long sob, long soh, long dob, long doh)
{
  __shared__ u16 tile[64*72];
  int z = blockIdx.z, b_ = z / Hh, h_ = z % Hh;
  const u16* S_ = src + (long)b_*sob + (long)h_*soh;
  u16* D_ = dst + (long)b_*dob + (long)h_*doh;
  int r0 = blockIdx.y * 64, c0 = blockIdx.x * 64;
  int tid = threadIdx.x;
  for (int idx = tid; idx < 512; idx += 256){
    int r = idx >> 3, c = (idx & 7) << 3;
    *(u16x8*)&tile[r*72 + c] = *(const u16x8*)&S_[(long)(r0 + r)*lds_ + c0 + c];
  }
  __syncthreads();
  for (int idx = tid; idx < 512; idx += 256){
    int c = idx >> 3, r = (idx & 7) << 3;
    u16x8 v;
#pragma unroll
    for (int e = 0; e < 8; e++) v[e] = tile[(r + e)*72 + c];
    *(u16x8*)&D_[(long)(c0 + c)*ldd + r0 + r] = v;
  }
}

// ---------------------------------------------------------------- fp32 src -> bf16 transposed dst
__global__ __launch_bounds__(256) void transpose_cvt_k(
    const float* __restrict__ src, u16* __restrict__ dst, int lds_, int ldd)
{
  __shared__ u16 tile[64*72];
  int r0 = blockIdx.y * 64, c0 = blockIdx.x * 64;
  int tid = threadIdx.x;
  for (int idx = tid; idx < 512; idx += 256){
    int r = idx >> 3, c = (idx & 7) << 3;
    const float* s = &src[(long)(r0 + r)*lds_ + c0 + c];
#pragma unroll
    for (int e = 0; e < 8; e++) tile[r*72 + c + e] = f2b(s[e]);
  }
  __syncthreads();
  for (int idx = tid; idx < 512; idx += 256){
    int c = idx >> 3, r = (idx & 7) << 3;
    u16x8 v;
#pragma unroll
    for (int e = 0; e < 8; e++) v[e] = tile[(r + e)*72 + c];
    *(u16x8*)&dst[(long)(c0 + c)*ldd + r0 + r] = v;
  }
}

// ---------------------------------------------------------------- flat fp32 -> bf16
__global__ __launch_bounds__(256) void cvt_k(const float* __restrict__ src, u16* __restrict__ dst)
{
  long i = ((long)blockIdx.x*256 + threadIdx.x) * 4;
  float4 v = *(const float4*)&src[i];
  u16x4 o; o[0] = f2b(v.x); o[1] = f2b(v.y); o[2] = f2b(v.z); o[3] = f2b(v.w);
  *(u16x4*)&dst[i] = o;
}

// ---------------------------------------------------------------- LayerNorm row=1024, fp32 in, bf16 out
__global__ __launch_bounds__(256) void ln_k(const float* __restrict__ src, const float* __restrict__ g,
                                            const float* __restrict__ be, u16* __restrict__ out)
{
  long base = (long)blockIdx.x * 1024;
  int tid = threadIdx.x;
  const float* s = src + base + tid*4;
  float v[4] = {s[0], s[1], s[2], s[3]};
  float s1 = v[0]+v[1]+v[2]+v[3];
  float s2 = v[0]*v[0]+v[1]*v[1]+v[2]*v[2]+v[3]*v[3];
  block_red2(s1, s2);
  float mu = s1 * (1.f/1024.f);
  float var = s2 * (1.f/1024.f) - mu*mu;
  float rs = rsqrtf(var + 1e-5f);
#pragma unroll
  for (int e = 0; e < 4; e++){
    int col = tid*4 + e;
    out[base + col] = f2b((v[e]-mu)*rs*g[col] + be[col]);
  }
}

// ---------------------------------------------------------------- out = resid + LN(sum4(go) + xn + bias)  (fp32 out)
__global__ __launch_bounds__(256) void add_ln_k(const float* __restrict__ go,
    const u16* __restrict__ xn, const float* __restrict__ bias,
    const float* __restrict__ g, const float* __restrict__ be,
    const float* __restrict__ resid, float* __restrict__ outp)
{
  const long PS = 2097152;
  long base = (long)blockIdx.x * 1024;
  int tid = threadIdx.x;
  float v[4];
#pragma unroll
  for (int e = 0; e < 4; e++){
    int col = tid*4 + e;
    long idx = base + col;
    v[e] = go[idx] + go[idx + PS] + go[idx + 2*PS] + go[idx + 3*PS] + b2f(xn[idx]) + bias[col];
  }
  float s1 = v[0]+v[1]+v[2]+v[3];
  float s2 = v[0]*v[0]+v[1]*v[1]+v[2]*v[2]+v[3]*v[3];
  block_red2(s1, s2);
  float mu = s1 * (1.f/1024.f);
  float var = s2 * (1.f/1024.f) - mu*mu;
  float rs = rsqrtf(var + 1e-5f);
#pragma unroll
  for (int e = 0; e < 4; e++){
    int col = tid*4 + e;
    outp[base + col] = resid[base + col] + (v[e]-mu)*rs*g[col] + be[col];
  }
}

// ---------------------------------------------------------------- QQ = [q+u | shifted(q+v)]  (B,S,H,128)
__global__ __launch_bounds__(256) void build_qq(const u16* __restrict__ q, const float* __restrict__ u,
                                                const float* __restrict__ v, u16* __restrict__ QQ)
{
  int bi = blockIdx.x;
  long qrow = (long)bi * 1024;
  long obase = (long)bi * 2048;
  int n = bi + 2;
  int bp = n / 1025, ip = n % 1025;
  long qsrc = ip ? ((long)(bp*1024 + ip - 1)) * 1024 : -1;
  for (int t = threadIdx.x; t < 2048; t += 256){
    int h = t >> 7, e = t & 127;
    float val;
    if (e < 64) val = b2f(q[qrow + h*64 + e]) + u[h*64 + e];
    else {
      int d = e - 64;
      val = (qsrc < 0) ? 0.f : b2f(q[qsrc + h*64 + d]) + v[h*64 + d];
    }
    QQ[obase + t] = f2b(val);
  }
}

// ---------------------------------------------------------------- BB = [k | pos_emb]  (B,St,H,128)
__global__ __launch_bounds__(256) void build_bb(const u16* __restrict__ kv, const float* __restrict__ pe,
                                                u16* __restrict__ BB)
{
  int bj = blockIdx.x;
  int j = bj & 2047;
  long kvrow = (long)bj * 2048;
  long obase = (long)bj * 2048;
  for (int t = threadIdx.x; t < 2048; t += 256){
    int h = t >> 7, e = t & 127;
    u16 val = (e < 64) ? kv[kvrow + h*64 + e] : f2b(pe[(long)j*1024 + h*64 + (e - 64)]);
    BB[obase + t] = val;
  }
}

// ---------------------------------------------------------------- gelu(exact) + bias, fp32 in, bf16 out
__global__ __launch_bounds__(256) void gelu_k(const float* __restrict__ f1, const float* __restrict__ b1,
                                              u16* __restrict__ h1)
{
  long i = (long)blockIdx.x*256 + threadIdx.x;
  float x = f1[i] + b1[i & 4095];
  h1[i] = f2b(0.5f * x * (1.f + erff(x * 0.70710678118654752f)));
}

// ---------------------------------------------------------------- out3 = out2 + sum4(f2) + b2  (fp32 out)
__global__ __launch_bounds__(256) void final_k(const float* __restrict__ out2, const float* __restrict__ f2,
                                               const float* __restrict__ b2v, float* __restrict__ outp)
{
  const long PS = 2097152;
  long i = (long)blockIdx.x*256 + threadIdx.x;
  outp[i] = out2[i] + f2[i] + f2[i + PS] + f2[i + 2*PS] + f2[i + 3*PS] + b2v[i & 1023];
}

// ================================================================ host
extern "C" void kernel_launch(void* const* d_in, const int* in_sizes, int n_in,
                              void* d_out, int out_size, void* d_ws, size_t ws_size,
                              hipStream_t stream)
{
  (void)in_sizes; (void)n_in; (void)out_size; (void)ws_size;
  // B=2 S=1024 M=1024 St=2048 D=DI=1024 H=16 DH=64 DFF=4096 ; ALL inputs/output fp32
  const float* X    = (const float*)d_in[0];
  const float* ENC  = (const float*)d_in[1];
  const float* PE   = (const float*)d_in[2];
  const float* Uu   = (const float*)d_in[3];
  const float* Vv   = (const float*)d_in[4];
  const float* MEM  = (const float*)d_in[5];
  const float* WQM  = (const float*)d_in[7];
  const float* WKVM = (const float*)d_in[8];
  const float* FCWM = (const float*)d_in[9];
  const float* FCBM = (const float*)d_in[10];
  const float* LNMG = (const float*)d_in[11];
  const float* LNMB = (const float*)d_in[12];
  const float* WQC  = (const float*)d_in[13];
  const float* WKVC = (const float*)d_in[14];
  const float* FCWC = (const float*)d_in[15];
  const float* FCBC = (const float*)d_in[16];
  const float* LNCG = (const float*)d_in[17];
  const float* LNCB = (const float*)d_in[18];
  const float* W1   = (const float*)d_in[19];
  const float* B1   = (const float*)d_in[20];
  const float* W2   = (const float*)d_in[21];
  const float* B2   = (const float*)d_in[22];
  const float* LN1G = (const float*)d_in[23];
  const float* LN1B = (const float*)d_in[24];
  const float* LN2G = (const float*)d_in[25];
  const float* LN2B = (const float*)d_in[26];
  const float* LN3G = (const float*)d_in[27];
  const float* LN3B = (const float*)d_in[28];
  float* OUT = (float*)d_out;
  char* W = (char*)d_ws;
  const size_t MB = 1ull << 20;

  // ---- layout, peak 122 MB (same as R9)
  u16*   wT_a  = (u16*)(W + 0*MB);
  u16*   wT_b  = (u16*)(W + 2*MB);
  u16*   wT_c  = (u16*)(W + 6*MB);
  u16*   w1T   = (u16*)(W + 0*MB);
  u16*   xn1   = (u16*)(W + 8*MB);
  u16*   q     = (u16*)(W + 12*MB);
  u16*   o_b   = (u16*)(W + 12*MB);
  u16*   kv    = (u16*)(W + 16*MB);
  float* outb  = (float*)(W + 24*MB);
  u16*   QQ    = (u16*)(W + 32*MB);
  u16*   xn2   = (u16*)(W + 32*MB);
  u16*   qc    = (u16*)(W + 36*MB);
  u16*   BB    = (u16*)(W + 40*MB);
  u16*   kvc   = (u16*)(W + 40*MB);
  u16*   Vtc   = (u16*)(W + 48*MB);
  u16*   oc    = (u16*)(W + 52*MB);
  u16*   Vt    = (u16*)(W + 56*MB);
  u16*   w2T   = (u16*)(W + 56*MB);
  float* mzb   = (float*)(W + 64*MB);
  u16*   memb  = (u16*)(W + 68*MB);
  u16*   encb  = (u16*)(W + 68*MB);
  float* opart = (float*)(W + 66*MB);    // 2 partials x 8 MB (dead before ofc is written)
  float* ofc   = (float*)(W + 66*MB);    // 4 partials x 8 MB
  float* f1    = (float*)(W + 66*MB);
  float* f2    = (float*)(W + 66*MB);    // 4 partials x 8 MB
  u16*   h1    = (u16*)(W + 98*MB);
  float* out2b = (float*)(W + 114*MB);

  // ================= MHA (Transformer-XL relative attention) =================
  transpose_cvt_k<<<dim3(16,16),256,0,stream>>>(WQM,  wT_a, 1024,1024);
  transpose_cvt_k<<<dim3(32,16),256,0,stream>>>(WKVM, wT_b, 2048,1024);
  transpose_cvt_k<<<dim3(16,16),256,0,stream>>>(FCWM, wT_c, 1024,1024);
  cvt_k<<<2048,256,0,stream>>>(MEM, memb);
  ln_k<<<2048,256,0,stream>>>(X, LN1G, LN1B, xn1);
  gemm_bt<2,2,true><<<dim3(8,16,1),256,0,stream>>>(xn1, wT_a, q, 1024, 1024,1024,1024, 1, 0,0,0,0,0,0);
  gemm_bt<2,2,true><<<dim3(16,8,2),256,0,stream>>>(memb, wT_b, kv, 1024, 1024,1024,2048, 1,
      1048576,0, 0,0, 4194304,0);
  gemm_bt<2,2,true><<<dim3(16,8,2),256,0,stream>>>(xn1, wT_b, kv + (size_t)1024*2048, 1024, 1024,1024,2048, 1,
      1048576,0, 0,0, 4194304,0);
  build_qq<<<2048,256,0,stream>>>(q, Uu, Vv, QQ);
  build_bb<<<4096,256,0,stream>>>(kv, PE, BB);
  transpose_k<<<dim3(1,32,32),256,0,stream>>>(kv + 1024, Vt, 2048, 2048, 16,
      4194304,64, 2097152,131072);
  attn_passA<128,true><<<dim3(32,32),256,0,stream>>>(BB, QQ, mzb, 2048, 2048, 2048,
      4194304,128, 2097152,128, 16, 0.125f, 65536);
  attn_passB<128,true><<<dim3(16,32,2),256,0,stream>>>(BB, QQ, Vt, mzb, opart, 2048,
      2048,2048,2048,1024, 4194304,128, 2097152,128, 2097152,131072, 1048576,64, 16, 0.125f, 65536,
      8, 2097152);
  combine_o<<<2048,256,0,stream>>>(opart, o_b);
  gemm_bt<2,2,false><<<dim3(8,16,4),256,0,stream>>>(o_b, wT_c, ofc, 256, 1024,1024,1024, 4,
      0,256, 0,256, 0,2097152);
  add_ln_k<<<2048,256,0,stream>>>(ofc, xn1, FCBM, LNMG, LNMB, X, outb);

  // ================= cross attention =================
  transpose_cvt_k<<<dim3(16,16),256,0,stream>>>(WQC,  wT_a, 1024,1024);
  transpose_cvt_k<<<dim3(32,16),256,0,stream>>>(WKVC, wT_b, 2048,1024);
  transpose_cvt_k<<<dim3(16,16),256,0,stream>>>(FCWC, wT_c, 1024,1024);
  cvt_k<<<2048,256,0,stream>>>(ENC, encb);
  ln_k<<<2048,256,0,stream>>>(outb, LN2G, LN2B, xn2);
  gemm_bt<2,2,true><<<dim3(8,16,1),256,0,stream>>>(xn2, wT_a, qc, 1024, 1024,1024,1024, 1, 0,0,0,0,0,0);
  gemm_bt<2,2,true><<<dim3(16,16,1),256,0,stream>>>(encb, wT_b, kvc, 1024, 1024,1024,2048, 1, 0,0,0,0,0,0);
  transpose_k<<<dim3(1,16,32),256,0,stream>>>(kvc + 1024, Vtc, 2048, 1024, 16,
      2097152,64, 1048576,65536);
  attn_passA<64,false><<<dim3(16,32),256,0,stream>>>(kvc, qc, mzb, 1024, 2048, 1024,
      2097152,64, 1048576,64, 16, 0.125f, 32768);
  attn_passB<64,false><<<dim3(16,32,2),256,0,stream>>>(kvc, qc, Vtc, mzb, opart, 1024,
      2048,1024,1024,1024, 2097152,64, 1048576,64, 1048576,65536, 1048576,64, 16, 0.125f, 32768,
      4, 2097152);
  combine_o<<<2048,256,0,stream>>>(opart, oc);
  gemm_bt<2,2,false><<<dim3(8,16,4),256,0,stream>>>(oc, wT_c, ofc, 256, 1024,1024,1024, 4,
      0,256, 0,256, 0,2097152);
  add_ln_k<<<2048,256,0,stream>>>(ofc, xn2, FCBC, LNCG, LNCB, outb, out2b);

  // ================= FFN =================
  transpose_cvt_k<<<dim3(64,16),256,0,stream>>>(W1, w1T, 4096,1024);
  transpose_cvt_k<<<dim3(16,64),256,0,stream>>>(W2, w2T, 1024,4096);
  ln_k<<<2048,256,0,stream>>>(out2b, LN3G, LN3B, xn2);
  gemm_bt<2,2,false><<<dim3(32,16,1),256,0,stream>>>(xn2, w1T, f1, 1024, 1024,1024,4096, 1, 0,0,0,0,0,0);
  gelu_k<<<32768,256,0,stream>>>(f1, B1, h1);
  gemm_bt<2,2,false><<<dim3(8,16,4),256,0,stream>>>(h1, w2T, f2, 1024, 4096,4096,1024, 4,
      0,1024, 0,1024, 0,2097152);
  final_k<<<8192,256,0,stream>>>(out2b, f2, B2, OUT);
}

// Round 10
// 663.027 us; speedup vs baseline: 1.0087x; 1.0087x over previous
//
#include <hip/hip_runtime.h>

typedef unsigned short u16;
typedef __attribute__((ext_vector_type(4))) unsigned short u16x4;
typedef __attribute__((ext_vector_type(8))) unsigned short u16x8;
typedef __attribute__((ext_vector_type(8))) __bf16 bf16x8;
typedef __attribute__((ext_vector_type(4))) float f32x4;

#define DEV __device__ __forceinline__

DEV float b2f(u16 u){ union{ unsigned int i; float f; } x; x.i = ((unsigned int)u) << 16; return x.f; }
DEV u16 f2b(float f){ unsigned int x = __float_as_uint(f); return (u16)((x + 0x7fffu + ((x >> 16) & 1u)) >> 16); }
DEV u16 f2bc(float f){ __bf16 h = (__bf16)f; return *(u16*)&h; }   // native RNE cvt (1 VALU op)

// T1: XCD-aware block remap. Blocks sharing `bh` (same K/V/Q panels) are clustered on
// one XCD so its private L2 holds the panel once, instead of all 8 XCDs streaming it
// from HBM independently. R14 measured: FETCH 99MB -> 16.7MB (6x), passB 84 -> 78us.
// Bijective when total%8==0 and nbh%8==0 (all our grids satisfy this).
DEV void xcd_remap(int nx, int nbh, int nz, int& x, int& bh, int& z){
  int hwid = blockIdx.x + nx*(blockIdx.y + nbh*blockIdx.z);
  int xcd = hwid & 7, slot = hwid >> 3;
  int bhper = nbh >> 3;
  int pg = nx*nz;
  bh = xcd*bhper + slot/pg;
  int rem = slot % pg;
  z = rem / nx;
  x = rem % nx;
}

// ---------------------------------------------------------------- block reduce (256 thr)
DEV void block_red2(float& s, float& q){
#pragma unroll
  for (int off = 32; off; off >>= 1){ s += __shfl_down(s, off); q += __shfl_down(q, off); }
  __shared__ float sh1[4], sh2[4];
  int lane = threadIdx.x & 63, w = threadIdx.x >> 6;
  if (lane == 0){ sh1[w] = s; sh2[w] = q; }
  __syncthreads();
  s = sh1[0] + sh1[1] + sh1[2] + sh1[3];
  q = sh2[0] + sh2[1] + sh2[2] + sh2[3];
}

// ---------------------------------------------------------------- GEMM  C = A[M,K] * B[N,K]^T
// m97 recipe: async global->LDS (width 16), unpadded lane-contiguous LDS tiles.
// EPI: 0 = fp32 store, 1 = bf16 store, 2 = bf16 gelu(acc + bias[col]) store (R16:
// fuses gelu_k into the FFN1 epilogue — deletes 84MB of HBM round-trip traffic).
// (no setprio here: m190 measured setprio NULL/negative on barrier-lockstep GEMM)
template<int WM, int WN, int EPI>
__global__ __launch_bounds__(WM*WN*64) void gemm_bt(
    const u16* __restrict__ A, const u16* __restrict__ Bm, void* __restrict__ Cp,
    const float* __restrict__ bias,
    int K, int lda, int ldb, int ldc, int Hh,
    long aob, long aoh, long bob, long boh, long cob, long coh)
{
  constexpr int BM = WM*64, BN = WN*64, BK = 64, NW = WM*WN;
  __shared__ u16 At[BM*64];
  __shared__ u16 Bt[BN*64];
  int z = blockIdx.z, b_ = z / Hh, h_ = z % Hh;
  const u16* Ab = A + (long)b_*aob + (long)h_*aoh;
  const u16* Bb = Bm + (long)b_*bob + (long)h_*boh;
  long cbase = (long)b_*cob + (long)h_*coh;
  int m0 = blockIdx.y * BM, n0 = blockIdx.x * BN;
  int tid = threadIdx.x, lane = tid & 63, wv = tid >> 6;
  int wm = wv / WN, wn = wv % WN;
  f32x4 acc[4][4];
  f32x4 z4 = {0.f, 0.f, 0.f, 0.f};
#pragma unroll
  for (int a = 0; a < 4; a++)
#pragma unroll
    for (int b = 0; b < 4; b++) acc[a][b] = z4;
  int lr = lane & 15, lk8 = (lane >> 4) * 8;
  int rq = lane >> 3, cq = (lane & 7) << 3;      // lane -> (row-in-8, col-16B) of one inst
  for (int k0 = 0; k0 < K; k0 += BK){
    __syncthreads();                             // prev MFMA reads done before overwrite
#pragma unroll
    for (int q = wv; q < BM/8; q += NW){
      const u16* g = &Ab[(long)(m0 + q*8 + rq)*lda + k0 + cq];
      __builtin_amdgcn_global_load_lds((const __attribute__((address_space(1))) void*)g,
          (__attribute__((address_space(3))) void*)&At[q*512], 16, 0, 0);
    }
#pragma unroll
    for (int q = wv; q < BN/8; q += NW){
      const u16* g = &Bb[(long)(n0 + q*8 + rq)*ldb + k0 + cq];
      __builtin_amdgcn_global_load_lds((const __attribute__((address_space(1))) void*)g,
          (__attribute__((address_space(3))) void*)&Bt[q*512], 16, 0, 0);
    }
    __syncthreads();                             // drains vmcnt (loads landed in LDS)
#pragma unroll
    for (int kk = 0; kk < BK; kk += 32){
      bf16x8 af[4], bfr[4];
#pragma unroll
      for (int mi = 0; mi < 4; mi++) af[mi]  = *(bf16x8*)&At[(wm*64 + mi*16 + lr)*64 + kk + lk8];
#pragma unroll
      for (int ni = 0; ni < 4; ni++) bfr[ni] = *(bf16x8*)&Bt[(wn*64 + ni*16 + lr)*64 + kk + lk8];
#pragma unroll
      for (int mi = 0; mi < 4; mi++)
#pragma unroll
        for (int ni = 0; ni < 4; ni++)
          acc[mi][ni] = __builtin_amdgcn_mfma_f32_16x16x32_bf16(af[mi], bfr[ni], acc[mi][ni], 0, 0, 0);
    }
  }
  int orow = (lane >> 4) * 4, ocol = lane & 15;
#pragma unroll
  for (int mi = 0; mi < 4; mi++)
#pragma unroll
    for (int ni = 0; ni < 4; ni++){
      int row = m0 + wm*64 + mi*16 + orow;
      int col = n0 + wn*64 + ni*16 + ocol;
      long cidx = cbase + (long)row*ldc + col;
#pragma unroll
      for (int r = 0; r < 4; r++){
        float vv = acc[mi][ni][r];
        if (EPI == 2){
          float x = vv + bias[col];
          ((u16*)Cp)[cidx + (long)r*ldc] = f2bc(0.5f * x * (1.f + erff(x * 0.70710678118654752f)));
        }
        else if (EPI == 1) ((u16*)Cp)[cidx + (long)r*ldc] = f2bc(vv);
        else               ((float*)Cp)[cidx + (long)r*ldc] = vv;
      }
    }
}

// ---------------------------------------------------------------- fused attention
// Pass A: per (b,h,j-tile of 64): m_j, 1/Z_j over all i (masked). 4 waves x 16 j-rows.
// R9 proven form: batched register staging + 1-tile-ahead prefetch, reg-resident K.
// R14: + T1 XCD remap.  R15: + T5 setprio around the QK^T MFMA cluster.
template<int KD, bool MASK>
__global__ __launch_bounds__(256) void attn_passA(
    const u16* __restrict__ Kp, const u16* __restrict__ Qp, float* __restrict__ mz,
    int J, int kld, int qld,
    long kob, long koh, long qob, long qoh, int H, float scale, int mztot)
{
  constexpr int KP = KD + 8;
  constexpr int RCH = KD / 8;
  constexpr int QREG = KD / 16;            // u16x8 regs per thread for the 128-row Q tile
  __shared__ u16 Qt[128*KP];
  int bx, bh, bz;
  xcd_remap(gridDim.x, gridDim.y, gridDim.z, bx, bh, bz);
  int b = bh / H, h = bh % H;
  const u16* Kb = Kp + (long)b*kob + (long)h*koh;
  const u16* Qb = Qp + (long)b*qob + (long)h*qoh;
  int j0 = bx * 64;
  int tid = threadIdx.x, lane = tid & 63, w = tid >> 6;
  int lr = lane & 15, lk8 = (lane >> 4) * 8;
  bf16x8 ak[KD/32];
  {
    const u16* kr = &Kb[(long)(j0 + w*16 + lr)*kld];
#pragma unroll
    for (int kk = 0; kk < KD/32; kk++) ak[kk] = *(const bf16x8*)&kr[kk*32 + lk8];
  }
  float m_run[4], z_run[4];
#pragma unroll
  for (int r = 0; r < 4; r++){ m_run[r] = -3.0e38f; z_run[r] = 0.f; }
  f32x4 zz = {0.f,0.f,0.f,0.f};
  int itLo = 0;
  if (MASK){ int tt = j0 - 1151; itLo = tt > 0 ? (tt + 127)/128 : 0; }
  u16x8 qreg[QREG];
#pragma unroll
  for (int qq = 0; qq < QREG; qq++){
    int idx = tid + qq*256; int r = idx / RCH, c = (idx % RCH) * 8;
    qreg[qq] = *(const u16x8*)&Qb[(long)(itLo*128 + r)*qld + c];
  }
  for (int it = itLo; it < 8; it++){
    __syncthreads();                       // prior Qt reads done before overwrite
#pragma unroll
    for (int qq = 0; qq < QREG; qq++){
      int idx = tid + qq*256; int r = idx / RCH, c = (idx % RCH) * 8;
      *(u16x8*)&Qt[r*KP + c] = qreg[qq];
    }
    if (it + 1 < 8){
#pragma unroll
      for (int qq = 0; qq < QREG; qq++){
        int idx = tid + qq*256; int r = idx / RCH, c = (idx % RCH) * 8;
        qreg[qq] = *(const u16x8*)&Qb[(long)((it+1)*128 + r)*qld + c];
      }
    }
    __syncthreads();                       // Qt ready
    f32x4 acc[8];
#pragma unroll
    for (int ni = 0; ni < 8; ni++) acc[ni] = zz;
    __builtin_amdgcn_s_setprio(1);         // T5: favor this wave's compute phase
#pragma unroll
    for (int kk = 0; kk < KD; kk += 32){
      bf16x8 bq[8];
#pragma unroll
      for (int ni = 0; ni < 8; ni++) bq[ni] = *(bf16x8*)&Qt[(ni*16 + lr)*KP + kk + lk8];
#pragma unroll
      for (int ni = 0; ni < 8; ni++)
        acc[ni] = __builtin_amdgcn_mfma_f32_16x16x32_bf16(ak[kk/32], bq[ni], acc[ni], 0, 0, 0);
    }
    __builtin_amdgcn_s_setprio(0);
#pragma unroll
    for (int r = 0; r < 4; r++){
      int jg = j0 + w*16 + ((lane >> 4) << 2) + r;
      float sv[8]; float tm = -3.0e38f;
#pragma unroll
      for (int ni = 0; ni < 8; ni++){
        int ig = it*128 + ni*16 + (lane & 15);
        float s = acc[ni][r] * scale;
        bool val = (!MASK) || (ig >= jg - 1024);
        sv[ni] = val ? s : -3.0e38f;
        tm = fmaxf(tm, sv[ni]);
      }
#pragma unroll
      for (int off = 1; off < 16; off <<= 1) tm = fmaxf(tm, __shfl_xor(tm, off));
      float mn = fmaxf(m_run[r], tm);
      float zt = 0.f;
#pragma unroll
      for (int ni = 0; ni < 8; ni++)
        zt += (sv[ni] > -1.0e37f) ? __expf(sv[ni] - mn) : 0.f;
#pragma unroll
      for (int off = 1; off < 16; off <<= 1) zt += __shfl_xor(zt, off);
      z_run[r] = z_run[r] * __expf(m_run[r] - mn) + zt;
      m_run[r] = mn;
    }
  }
  if ((lane & 15) == 0){
#pragma unroll
    for (int r = 0; r < 4; r++){
      int jg = j0 + w*16 + ((lane >> 4) << 2) + r;
      mz[(long)bh*J + jg] = m_run[r];
      mz[(long)mztot + (long)bh*J + jg] = 1.f / z_run[r];
    }
  }
}

// Pass B: per (b,h,i-tile of 64, j-half). R9 proven body (KVBLK=128, batched register
// staging + 1-tile prefetch, reg-resident Q, LDS-staged K/V with K/P alias).
// R14: + T1 XCD remap; native (__bf16) RNE P-write.  R15: + T5 setprio around MFMA.
template<int KD, bool MASK>
__global__ __launch_bounds__(256) void attn_passB(
    const u16* __restrict__ Kp, const u16* __restrict__ Qp, const u16* __restrict__ Vtp,
    const float* __restrict__ mz, float* __restrict__ Op,
    int J, int kld, int qld, int vld, int oldd,
    long kob, long koh, long qob, long qoh, long vob, long voh, long oob, long ooh,
    int H, float scale, int mztot, int jtHalf, long opstride)
{
  constexpr int KP = KD + 8, PSTR = 140, VSTR = 136;
  constexpr int RCH = KD / 8;
  constexpr int KREG = KD / 16;            // u16x8 regs per thread for the 128-row K tile
  __shared__ u16 PK[128*KP];       // K tile (128 x KP) ; aliased by P tile (64 x PSTR)
  __shared__ u16 Vtt[64*VSTR];
  u16* Kt = PK;
  u16* Pt = PK;
  int bx, bh, jh;
  xcd_remap(gridDim.x, gridDim.y, gridDim.z, bx, bh, jh);
  int b = bh / H, h = bh % H;
  const u16* Kb = Kp + (long)b*kob + (long)h*koh;
  const u16* Qb = Qp + (long)b*qob + (long)h*qoh;
  const u16* Vb = Vtp + (long)b*vob + (long)h*voh;
  float* Ob = Op + (long)jh*opstride + (long)b*oob + (long)h*ooh;
  const float* mzm = mz + (long)bh*J;
  const float* mzz = mz + (long)mztot + (long)bh*J;
  int i0 = bx * 64;
  int tid = threadIdx.x, lane = tid & 63, w = tid >> 6;
  int lr = lane & 15, lk8 = (lane >> 4) * 8;
  // Q fragment in registers: wave's own 16 i-rows, reused across all j-tiles
  bf16x8 aq[KD/32];
  {
    const u16* qr = &Qb[(long)(i0 + w*16 + lr)*qld];
#pragma unroll
    for (int kk = 0; kk < KD/32; kk++) aq[kk] = *(const bf16x8*)&qr[kk*32 + lk8];
  }
  f32x4 acc_o[4];
  f32x4 zz = {0.f,0.f,0.f,0.f};
#pragma unroll
  for (int nd = 0; nd < 4; nd++) acc_o[nd] = zz;
  int lo = jh * jtHalf, hi = lo + jtHalf;
  if (MASK){ int lim = (i0 + 1087)/128 + 1; hi = hi < lim ? hi : lim; }
  if (lo < hi){
    u16x8 kreg[KREG];
    u16x8 vreg[4];
#pragma unroll
    for (int qq = 0; qq < KREG; qq++){
      int idx = tid + qq*256; int r = idx / RCH, c = (idx % RCH) * 8;
      kreg[qq] = *(const u16x8*)&Kb[(long)(lo*128 + r)*kld + c];
    }
#pragma unroll
    for (int qq = 0; qq < 4; qq++){
      int idx = tid + qq*256; int r = idx >> 4, c = (idx & 15) << 3;
      vreg[qq] = *(const u16x8*)&Vb[(long)r*vld + lo*128 + c];
    }
    for (int jt = lo; jt < hi; jt++){
      __syncthreads();                     // prior P/Vt reads done before restage
#pragma unroll
      for (int qq = 0; qq < KREG; qq++){
        int idx = tid + qq*256; int r = idx / RCH, c = (idx % RCH) * 8;
        *(u16x8*)&Kt[r*KP + c] = kreg[qq];
      }
#pragma unroll
      for (int qq = 0; qq < 4; qq++){
        int idx = tid + qq*256; int r = idx >> 4, c = (idx & 15) << 3;
        *(u16x8*)&Vtt[r*VSTR + c] = vreg[qq];
      }
      if (jt + 1 < hi){                    // prefetch next tile during this tile's compute
#pragma unroll
        for (int qq = 0; qq < KREG; qq++){
          int idx = tid + qq*256; int r = idx / RCH, c = (idx % RCH) * 8;
          kreg[qq] = *(const u16x8*)&Kb[(long)((jt+1)*128 + r)*kld + c];
        }
#pragma unroll
        for (int qq = 0; qq < 4; qq++){
          int idx = tid + qq*256; int r = idx >> 4, c = (idx & 15) << 3;
          vreg[qq] = *(const u16x8*)&Vb[(long)r*vld + (jt+1)*128 + c];
        }
      }
      __syncthreads();                     // K/V LDS ready
      float mjv[8], zjv[8];
#pragma unroll
      for (int ni = 0; ni < 8; ni++){      // issue before MFMA: latency hides under QK^T
        int jg = jt*128 + ni*16 + (lane & 15);
        mjv[ni] = mzm[jg]; zjv[ni] = mzz[jg];
      }
      // S tile: A = Q regs (own wave's 16 i-rows), B = K (128 j)
      f32x4 acc[8];
#pragma unroll
      for (int ni = 0; ni < 8; ni++) acc[ni] = zz;
      __builtin_amdgcn_s_setprio(1);       // T5
#pragma unroll
      for (int kk = 0; kk < KD; kk += 32){
        bf16x8 bk[8];
#pragma unroll
        for (int ni = 0; ni < 8; ni++) bk[ni] = *(bf16x8*)&Kt[(ni*16 + lr)*KP + kk + lk8];
#pragma unroll
        for (int ni = 0; ni < 8; ni++)
          acc[ni] = __builtin_amdgcn_mfma_f32_16x16x32_bf16(aq[kk/32], bk[ni], acc[ni], 0, 0, 0);
      }
      __builtin_amdgcn_s_setprio(0);
      __syncthreads();                     // K reads done before P overwrite (alias)
#pragma unroll
      for (int ni = 0; ni < 8; ni++){
        int jg = jt*128 + ni*16 + (lane & 15);
#pragma unroll
        for (int r = 0; r < 4; r++){
          int ig = i0 + w*16 + ((lane >> 4) << 2) + r;
          bool val = (!MASK) || (ig >= jg - 1024);
          float p = val ? __expf(acc[ni][r] * scale - mjv[ni]) * zjv[ni] : 0.f;
          Pt[(w*16 + ((lane >> 4) << 2) + r)*PSTR + ni*16 + (lane & 15)] = f2bc(p);
        }
      }
      // no barrier: P write->read is within-wave (own 16 rows), DS pipe is in-order
      // PV: A = P (own wave's 16 i-rows), B = Vt (64 d-rows)
      __builtin_amdgcn_s_setprio(1);       // T5
#pragma unroll
      for (int kk = 0; kk < 128; kk += 32){
        bf16x8 pa, vb[4];
        pa = *(bf16x8*)&Pt[(w*16 + lr)*PSTR + kk + lk8];
#pragma unroll
        for (int nd = 0; nd < 4; nd++) vb[nd] = *(bf16x8*)&Vtt[(nd*16 + lr)*VSTR + kk + lk8];
#pragma unroll
        for (int nd = 0; nd < 4; nd++)
          acc_o[nd] = __builtin_amdgcn_mfma_f32_16x16x32_bf16(pa, vb[nd], acc_o[nd], 0, 0, 0);
      }
      __builtin_amdgcn_s_setprio(0);
    }
  }
#pragma unroll
  for (int nd = 0; nd < 4; nd++)
#pragma unroll
    for (int r = 0; r < 4; r++){
      int ig = i0 + w*16 + ((lane >> 4) << 2) + r;
      int d = nd*16 + (lane & 15);
      Ob[(long)ig*oldd + d] = acc_o[nd][r];
    }
}

// ---------------------------------------------------------------- o = bf16(part0 + part1)
__global__ __launch_bounds__(256) void combine_o(const float* __restrict__ p, u16* __restrict__ o)
{
  const long PS = 2097152;
  long i = ((long)blockIdx.x*256 + threadIdx.x) * 4;
  const float* a = &p[i];
  const float* b = &p[i + PS];
  u16x4 r;
#pragma unroll
  for (int e = 0; e < 4; e++) r[e] = f2bc(a[e] + b[e]);
  *(u16x4*)&o[i] = r;
}

// ---------------------------------------------------------------- bf16 transpose dst[c,r]=src[r,c]
__global__ __launch_bounds__(256) void transpose_k(
    const u16* __restrict__ src, u16* __restrict__ dst,
    int lds_, int ldd, int Hh, long sob, long soh, long dob, long doh)
{
  __shared__ u16 tile[64*72];
  int z = blockIdx.z, b_ = z / Hh, h_ = z % Hh;
  const u16* S_ = src + (long)b_*sob + (long)h_*soh;
  u16* D_ = dst + (long)b_*dob + (long)h_*doh;
  int r0 = blockIdx.y * 64, c0 = blockIdx.x * 64;
  int tid = threadIdx.x;
  for (int idx = tid; idx < 512; idx += 256){
    int r = idx >> 3, c = (idx & 7) << 3;
    *(u16x8*)&tile[r*72 + c] = *(const u16x8*)&S_[(long)(r0 + r)*lds_ + c0 + c];
  }
  __syncthreads();
  for (int idx = tid; idx < 512; idx += 256){
    int c = idx >> 3, r = (idx & 7) << 3;
    u16x8 v;
#pragma unroll
    for (int e = 0; e < 8; e++) v[e] = tile[(r + e)*72 + c];
    *(u16x8*)&D_[(long)(c0 + c)*ldd + r0 + r] = v;
  }
}

// ---------------------------------------------------------------- fp32 src -> bf16 transposed dst
__global__ __launch_bounds__(256) void transpose_cvt_k(
    const float* __restrict__ src, u16* __restrict__ dst, int lds_, int ldd)
{
  __shared__ u16 tile[64*72];
  int r0 = blockIdx.y * 64, c0 = blockIdx.x * 64;
  int tid = threadIdx.x;
  for (int idx = tid; idx < 512; idx += 256){
    int r = idx >> 3, c = (idx & 7) << 3;
    const float* s = &src[(long)(r0 + r)*lds_ + c0 + c];
#pragma unroll
    for (int e = 0; e < 8; e++) tile[r*72 + c + e] = f2b(s[e]);
  }
  __syncthreads();
  for (int idx = tid; idx < 512; idx += 256){
    int c = idx >> 3, r = (idx & 7) << 3;
    u16x8 v;
#pragma unroll
    for (int e = 0; e < 8; e++) v[e] = tile[(r + e)*72 + c];
    *(u16x8*)&dst[(long)(c0 + c)*ldd + r0 + r] = v;
  }
}

// ---------------------------------------------------------------- flat fp32 -> bf16
__global__ __launch_bounds__(256) void cvt_k(const float* __restrict__ src, u16* __restrict__ dst)
{
  long i = ((long)blockIdx.x*256 + threadIdx.x) * 4;
  float4 v = *(const float4*)&src[i];
  u16x4 o; o[0] = f2b(v.x); o[1] = f2b(v.y); o[2] = f2b(v.z); o[3] = f2b(v.w);
  *(u16x4*)&dst[i] = o;
}

// ---------------------------------------------------------------- LayerNorm row=1024, fp32 in, bf16 out
__global__ __launch_bounds__(256) void ln_k(const float* __restrict__ src, const float* __restrict__ g,
                                            const float* __restrict__ be, u16* __restrict__ out)
{
  long base = (long)blockIdx.x * 1024;
  int tid = threadIdx.x;
  const float* s = src + base + tid*4;
  float v[4] = {s[0], s[1], s[2], s[3]};
  float s1 = v[0]+v[1]+v[2]+v[3];
  float s2 = v[0]*v[0]+v[1]*v[1]+v[2]*v[2]+v[3]*v[3];
  block_red2(s1, s2);
  float mu = s1 * (1.f/1024.f);
  float var = s2 * (1.f/1024.f) - mu*mu;
  float rs = rsqrtf(var + 1e-5f);
#pragma unroll
  for (int e = 0; e < 4; e++){
    int col = tid*4 + e;
    out[base + col] = f2b((v[e]-mu)*rs*g[col] + be[col]);
  }
}

// ---------------------------------------------------------------- out = resid + LN(sum4(go) + xn + bias)  (fp32 out)
__global__ __launch_bounds__(256) void add_ln_k(const float* __restrict__ go,
    const u16* __restrict__ xn, const float* __restrict__ bias,
    const float* __restrict__ g, const float* __restrict__ be,
    const float* __restrict__ resid, float* __restrict__ outp)
{
  const long PS = 2097152;
  long base = (long)blockIdx.x * 1024;
  int tid = threadIdx.x;
  float v[4];
#pragma unroll
  for (int e = 0; e < 4; e++){
    int col = tid*4 + e;
    long idx = base + col;
    v[e] = go[idx] + go[idx + PS] + go[idx + 2*PS] + go[idx + 3*PS] + b2f(xn[idx]) + bias[col];
  }
  float s1 = v[0]+v[1]+v[2]+v[3];
  float s2 = v[0]*v[0]+v[1]*v[1]+v[2]*v[2]+v[3]*v[3];
  block_red2(s1, s2);
  float mu = s1 * (1.f/1024.f);
  float var = s2 * (1.f/1024.f) - mu*mu;
  float rs = rsqrtf(var + 1e-5f);
#pragma unroll
  for (int e = 0; e < 4; e++){
    int col = tid*4 + e;
    outp[base + col] = resid[base + col] + (v[e]-mu)*rs*g[col] + be[col];
  }
}

// ---------------------------------------------------------------- QQ = [q+u | shifted(q+v)]  (B,S,H,128)
__global__ __launch_bounds__(256) void build_qq(const u16* __restrict__ q, const float* __restrict__ u,
                                                const float* __restrict__ v, u16* __restrict__ QQ)
{
  int bi = blockIdx.x;
  long qrow = (long)bi * 1024;
  long obase = (long)bi * 2048;
  int n = bi + 2;
  int bp = n / 1025, ip = n % 1025;
  long qsrc = ip ? ((long)(bp*1024 + ip - 1)) * 1024 : -1;
  for (int t = threadIdx.x; t < 2048; t += 256){
    int h = t >> 7, e = t & 127;
    float val;
    if (e < 64) val = b2f(q[qrow + h*64 + e]) + u[h*64 + e];
    else {
      int d = e - 64;
      val = (qsrc < 0) ? 0.f : b2f(q[qsrc + h*64 + d]) + v[h*64 + d];
    }
    QQ[obase + t] = f2b(val);
  }
}

// ---------------------------------------------------------------- BB = [k | pos_emb]  (B,St,H,128)
__global__ __launch_bounds__(256) void build_bb(const u16* __restrict__ kv, const float* __restrict__ pe,
                                                u16* __restrict__ BB)
{
  int bj = blockIdx.x;
  int j = bj & 2047;
  long kvrow = (long)bj * 2048;
  long obase = (long)bj * 2048;
  for (int t = threadIdx.x; t < 2048; t += 256){
    int h = t >> 7, e = t & 127;
    u16 val = (e < 64) ? kv[kvrow + h*64 + e] : f2b(pe[(long)j*1024 + h*64 + (e - 64)]);
    BB[obase + t] = val;
  }
}

// ---------------------------------------------------------------- out3 = out2 + sum4(f2) + b2  (fp32 out, float4)
__global__ __launch_bounds__(256) void final_k(const float* __restrict__ out2, const float* __restrict__ f2,
                                               const float* __restrict__ b2v, float* __restrict__ outp)
{
  const long PS = 2097152;
  long i = ((long)blockIdx.x*256 + threadIdx.x) * 4;
  float4 o2 = *(const float4*)&out2[i];
  float4 a0 = *(const float4*)&f2[i];
  float4 a1 = *(const float4*)&f2[i + PS];
  float4 a2 = *(const float4*)&f2[i + 2*PS];
  float4 a3 = *(const float4*)&f2[i + 3*PS];
  float4 bb = *(const float4*)&b2v[i & 1023];
  float4 r;
  r.x = o2.x + a0.x + a1.x + a2.x + a3.x + bb.x;
  r.y = o2.y + a0.y + a1.y + a2.y + a3.y + bb.y;
  r.z = o2.z + a0.z + a1.z + a2.z + a3.z + bb.z;
  r.w = o2.w + a0.w + a1.w + a2.w + a3.w + bb.w;
  *(float4*)&outp[i] = r;
}

// ================================================================ host
extern "C" void kernel_launch(void* const* d_in, const int* in_sizes, int n_in,
                              void* d_out, int out_size, void* d_ws, size_t ws_size,
                              hipStream_t stream)
{
  (void)in_sizes; (void)n_in; (void)out_size; (void)ws_size;
  // B=2 S=1024 M=1024 St=2048 D=DI=1024 H=16 DH=64 DFF=4096 ; ALL inputs/output fp32
  const float* X    = (const float*)d_in[0];
  const float* ENC  = (const float*)d_in[1];
  const float* PE   = (const float*)d_in[2];
  const float* Uu   = (const float*)d_in[3];
  const float* Vv   = (const float*)d_in[4];
  const float* MEM  = (const float*)d_in[5];
  const float* WQM  = (const float*)d_in[7];
  const float* WKVM = (const float*)d_in[8];
  const float* FCWM = (const float*)d_in[9];
  const float* FCBM = (const float*)d_in[10];
  const float* LNMG = (const float*)d_in[11];
  const float* LNMB = (const float*)d_in[12];
  const float* WQC  = (const float*)d_in[13];
  const float* WKVC = (const float*)d_in[14];
  const float* FCWC = (const float*)d_in[15];
  const float* FCBC = (const float*)d_in[16];
  const float* LNCG = (const float*)d_in[17];
  const float* LNCB = (const float*)d_in[18];
  const float* W1   = (const float*)d_in[19];
  const float* B1   = (const float*)d_in[20];
  const float* W2   = (const float*)d_in[21];
  const float* B2   = (const float*)d_in[22];
  const float* LN1G = (const float*)d_in[23];
  const float* LN1B = (const float*)d_in[24];
  const float* LN2G = (const float*)d_in[25];
  const float* LN2B = (const float*)d_in[26];
  const float* LN3G = (const float*)d_in[27];
  const float* LN3B = (const float*)d_in[28];
  float* OUT = (float*)d_out;
  char* W = (char*)d_ws;
  const size_t MB = 1ull << 20;

  // ---- layout, peak 122 MB (same as R9)
  u16*   wT_a  = (u16*)(W + 0*MB);
  u16*   wT_b  = (u16*)(W + 2*MB);
  u16*   wT_c  = (u16*)(W + 6*MB);
  u16*   w1T   = (u16*)(W + 0*MB);
  u16*   xn1   = (u16*)(W + 8*MB);
  u16*   q     = (u16*)(W + 12*MB);
  u16*   o_b   = (u16*)(W + 12*MB);
  u16*   kv    = (u16*)(W + 16*MB);
  float* outb  = (float*)(W + 24*MB);
  u16*   QQ    = (u16*)(W + 32*MB);
  u16*   xn2   = (u16*)(W + 32*MB);
  u16*   qc    = (u16*)(W + 36*MB);
  u16*   BB    = (u16*)(W + 40*MB);
  u16*   kvc   = (u16*)(W + 40*MB);
  u16*   Vtc   = (u16*)(W + 48*MB);
  u16*   oc    = (u16*)(W + 52*MB);
  u16*   Vt    = (u16*)(W + 56*MB);
  u16*   w2T   = (u16*)(W + 56*MB);
  float* mzb   = (float*)(W + 64*MB);
  u16*   memb  = (u16*)(W + 68*MB);
  u16*   encb  = (u16*)(W + 68*MB);
  float* opart = (float*)(W + 66*MB);    // 2 partials x 8 MB (dead before ofc is written)
  float* ofc   = (float*)(W + 66*MB);    // 4 partials x 8 MB
  float* f1    = (float*)(W + 66*MB);
  float* f2    = (float*)(W + 66*MB);    // 4 partials x 8 MB
  u16*   h1    = (u16*)(W + 98*MB);
  float* out2b = (float*)(W + 114*MB);

  // ================= MHA (Transformer-XL relative attention) =================
  transpose_cvt_k<<<dim3(16,16),256,0,stream>>>(WQM,  wT_a, 1024,1024);
  transpose_cvt_k<<<dim3(32,16),256,0,stream>>>(WKVM, wT_b, 2048,1024);
  transpose_cvt_k<<<dim3(16,16),256,0,stream>>>(FCWM, wT_c, 1024,1024);
  cvt_k<<<2048,256,0,stream>>>(MEM, memb);
  ln_k<<<2048,256,0,stream>>>(X, LN1G, LN1B, xn1);
  gemm_bt<2,2,1><<<dim3(8,16,1),256,0,stream>>>(xn1, wT_a, q, nullptr, 1024, 1024,1024,1024, 1, 0,0,0,0,0,0);
  gemm_bt<2,2,1><<<dim3(16,8,2),256,0,stream>>>(memb, wT_b, kv, nullptr, 1024, 1024,1024,2048, 1,
      1048576,0, 0,0, 4194304,0);
  gemm_bt<2,2,1><<<dim3(16,8,2),256,0,stream>>>(xn1, wT_b, kv + (size_t)1024*2048, nullptr, 1024, 1024,1024,2048, 1,
      1048576,0, 0,0, 4194304,0);
  build_qq<<<2048,256,0,stream>>>(q, Uu, Vv, QQ);
  build_bb<<<4096,256,0,stream>>>(kv, PE, BB);
  transpose_k<<<dim3(1,32,32),256,0,stream>>>(kv + 1024, Vt, 2048, 2048, 16,
      4194304,64, 2097152,131072);
  attn_passA<128,true><<<dim3(32,32),256,0,stream>>>(BB, QQ, mzb, 2048, 2048, 2048,
      4194304,128, 2097152,128, 16, 0.125f, 65536);
  attn_passB<128,true><<<dim3(16,32,2),256,0,stream>>>(BB, QQ, Vt, mzb, opart, 2048,
      2048,2048,2048,1024, 4194304,128, 2097152,128, 2097152,131072, 1048576,64, 16, 0.125f, 65536,
      8, 2097152);
  combine_o<<<2048,256,0,stream>>>(opart, o_b);
  gemm_bt<2,2,0><<<dim3(8,16,4),256,0,stream>>>(o_b, wT_c, ofc, nullptr, 256, 1024,1024,1024, 4,
      0,256, 0,256, 0,2097152);
  add_ln_k<<<2048,256,0,stream>>>(ofc, xn1, FCBM, LNMG, LNMB, X, outb);

  // ================= cross attention =================
  transpose_cvt_k<<<dim3(16,16),256,0,stream>>>(WQC,  wT_a, 1024,1024);
  transpose_cvt_k<<<dim3(32,16),256,0,stream>>>(WKVC, wT_b, 2048,1024);
  transpose_cvt_k<<<dim3(16,16),256,0,stream>>>(FCWC, wT_c, 1024,1024);
  cvt_k<<<2048,256,0,stream>>>(ENC, encb);
  ln_k<<<2048,256,0,stream>>>(outb, LN2G, LN2B, xn2);
  gemm_bt<2,2,1><<<dim3(8,16,1),256,0,stream>>>(xn2, wT_a, qc, nullptr, 1024, 1024,1024,1024, 1, 0,0,0,0,0,0);
  gemm_bt<2,2,1><<<dim3(16,16,1),256,0,stream>>>(encb, wT_b, kvc, nullptr, 1024, 1024,1024,2048, 1, 0,0,0,0,0,0);
  transpose_k<<<dim3(1,16,32),256,0,stream>>>(kvc + 1024, Vtc, 2048, 1024, 16,
      2097152,64, 1048576,65536);
  attn_passA<64,false><<<dim3(16,32),256,0,stream>>>(kvc, qc, mzb, 1024, 2048, 1024,
      2097152,64, 1048576,64, 16, 0.125f, 32768);
  attn_passB<64,false><<<dim3(16,32,2),256,0,stream>>>(kvc, qc, Vtc, mzb, opart, 1024,
      2048,1024,1024,1024, 2097152,64, 1048576,64, 1048576,65536, 1048576,64, 16, 0.125f, 32768,
      4, 2097152);
  combine_o<<<2048,256,0,stream>>>(opart, oc);
  gemm_bt<2,2,0><<<dim3(8,16,4),256,0,stream>>>(oc, wT_c, ofc, nullptr, 256, 1024,1024,1024, 4,
      0,256, 0,256, 0,2097152);
  add_ln_k<<<2048,256,0,stream>>>(ofc, xn2, FCBC, LNCG, LNCB, outb, out2b);

  // ================= FFN =================
  transpose_cvt_k<<<dim3(64,16),256,0,stream>>>(W1, w1T, 4096,1024);
  transpose_cvt_k<<<dim3(16,64),256,0,stream>>>(W2, w2T, 1024,4096);
  ln_k<<<2048,256,0,stream>>>(out2b, LN3G, LN3B, xn2);
  gemm_bt<2,2,2><<<dim3(32,16,1),256,0,stream>>>(xn2, w1T, h1, B1, 1024, 1024,1024,4096, 1, 0,0,0,0,0,0);
  gemm_bt<2,2,0><<<dim3(8,16,4),256,0,stream>>>(h1, w2T, f2, nullptr, 1024, 4096,4096,1024, 4,
      0,1024, 0,1024, 0,2097152);
  final_k<<<2048,256,0,stream>>>(out2b, f2, B2, OUT);
}

// Round 11
// 649.250 us; speedup vs baseline: 1.0301x; 1.0212x over previous
//
#include <hip/hip_runtime.h>

typedef unsigned short u16;
typedef __attribute__((ext_vector_type(4))) unsigned short u16x4;
typedef __attribute__((ext_vector_type(8))) unsigned short u16x8;
typedef __attribute__((ext_vector_type(8))) __bf16 bf16x8;
typedef __attribute__((ext_vector_type(4))) float f32x4;

#define DEV __device__ __forceinline__

DEV float b2f(u16 u){ union{ unsigned int i; float f; } x; x.i = ((unsigned int)u) << 16; return x.f; }
DEV u16 f2b(float f){ unsigned int x = __float_as_uint(f); return (u16)((x + 0x7fffu + ((x >> 16) & 1u)) >> 16); }
DEV u16 f2bc(float f){ __bf16 h = (__bf16)f; return *(u16*)&h; }   // native RNE cvt (1 VALU op)

// T1: XCD-aware block remap (attention form). Blocks sharing `bh` cluster on one XCD.
// R14 measured: FETCH 99MB -> 16.7MB (6x), passB 84 -> 78us.
DEV void xcd_remap(int nx, int nbh, int nz, int& x, int& bh, int& z){
  int hwid = blockIdx.x + nx*(blockIdx.y + nbh*blockIdx.z);
  int xcd = hwid & 7, slot = hwid >> 3;
  int bhper = nbh >> 3;
  int pg = nx*nz;
  bh = xcd*bhper + slot/pg;
  int rem = slot % pg;
  z = rem / nx;
  x = rem % nx;
}

// R17: T1 for GEMMs. Default dispatch round-robins consecutive blocks across the 8 XCDs,
// so the m-blocks sharing one B n-panel land on 8 DIFFERENT private L2s -> every XCD
// streams the whole weight matrix from HBM. Cluster instead: each XCD owns a contiguous
// chunk of the grid with x (n-dim) slowest -> per-XCD B-slice 0.25-1MB + A panel, both
// ~L2-resident. Bijective when total%8==0 (all call sites); runtime fallback otherwise.
DEV void gemm_remap(int& bx, int& by, int& bz){
  int nx = gridDim.x, ny = gridDim.y, nz = gridDim.z;
  int n = nx*ny*nz;
  if (n & 7){ bx = blockIdx.x; by = blockIdx.y; bz = blockIdx.z; return; }
  int id = blockIdx.x + nx*(blockIdx.y + ny*blockIdx.z);
  int chunk = n >> 3;
  int nid = (id & 7)*chunk + (id >> 3);
  int yz = ny*nz;
  bx = nid / yz;
  int rem = nid % yz;
  by = rem / nz;
  bz = rem % nz;
}

// ---------------------------------------------------------------- block reduce (256 thr)
DEV void block_red2(float& s, float& q){
#pragma unroll
  for (int off = 32; off; off >>= 1){ s += __shfl_down(s, off); q += __shfl_down(q, off); }
  __shared__ float sh1[4], sh2[4];
  int lane = threadIdx.x & 63, w = threadIdx.x >> 6;
  if (lane == 0){ sh1[w] = s; sh2[w] = q; }
  __syncthreads();
  s = sh1[0] + sh1[1] + sh1[2] + sh1[3];
  q = sh2[0] + sh2[1] + sh2[2] + sh2[3];
}

// ---------------------------------------------------------------- GEMM  C = A[M,K] * B[N,K]^T
// m97 recipe: async global->LDS (width 16), unpadded lane-contiguous LDS tiles.
// EPI: 0 = fp32 store, 1 = bf16 store, 2 = bf16 gelu(acc + bias[col]) store.
// A2 (R17): twin-A mode for the merged kv GEMM — h_ selects A (h_=0) vs A2 (h_=1),
// same B reused by all z-slices. Pass nullptr everywhere else.
// (no setprio here: m190 measured setprio NULL/negative on barrier-lockstep GEMM)
template<int WM, int WN, int EPI>
__global__ __launch_bounds__(WM*WN*64) void gemm_bt(
    const u16* __restrict__ A, const u16* __restrict__ A2,
    const u16* __restrict__ Bm, void* __restrict__ Cp,
    const float* __restrict__ bias,
    int K, int lda, int ldb, int ldc, int Hh,
    long aob, long aoh, long bob, long boh, long cob, long coh)
{
  constexpr int BM = WM*64, BN = WN*64, BK = 64, NW = WM*WN;
  __shared__ u16 At[BM*64];
  __shared__ u16 Bt[BN*64];
  int gx, gy, gz;
  gemm_remap(gx, gy, gz);
  int b_ = gz / Hh, h_ = gz % Hh;
  const u16* Abase = (A2 && h_) ? A2 : A;
  const u16* Ab = Abase + (long)b_*aob + (A2 ? 0 : (long)h_*aoh);
  const u16* Bb = Bm + (long)b_*bob + (long)h_*boh;
  long cbase = (long)b_*cob + (long)h_*coh;
  int m0 = gy * BM, n0 = gx * BN;
  int tid = threadIdx.x, lane = tid & 63, wv = tid >> 6;
  int wm = wv / WN, wn = wv % WN;
  f32x4 acc[4][4];
  f32x4 z4 = {0.f, 0.f, 0.f, 0.f};
#pragma unroll
  for (int a = 0; a < 4; a++)
#pragma unroll
    for (int b = 0; b < 4; b++) acc[a][b] = z4;
  int lr = lane & 15, lk8 = (lane >> 4) * 8;
  int rq = lane >> 3, cq = (lane & 7) << 3;      // lane -> (row-in-8, col-16B) of one inst
  for (int k0 = 0; k0 < K; k0 += BK){
    __syncthreads();                             // prev MFMA reads done before overwrite
#pragma unroll
    for (int q = wv; q < BM/8; q += NW){
      const u16* g = &Ab[(long)(m0 + q*8 + rq)*lda + k0 + cq];
      __builtin_amdgcn_global_load_lds((const __attribute__((address_space(1))) void*)g,
          (__attribute__((address_space(3))) void*)&At[q*512], 16, 0, 0);
    }
#pragma unroll
    for (int q = wv; q < BN/8; q += NW){
      const u16* g = &Bb[(long)(n0 + q*8 + rq)*ldb + k0 + cq];
      __builtin_amdgcn_global_load_lds((const __attribute__((address_space(1))) void*)g,
          (__attribute__((address_space(3))) void*)&Bt[q*512], 16, 0, 0);
    }
    __syncthreads();                             // drains vmcnt (loads landed in LDS)
#pragma unroll
    for (int kk = 0; kk < BK; kk += 32){
      bf16x8 af[4], bfr[4];
#pragma unroll
      for (int mi = 0; mi < 4; mi++) af[mi]  = *(bf16x8*)&At[(wm*64 + mi*16 + lr)*64 + kk + lk8];
#pragma unroll
      for (int ni = 0; ni < 4; ni++) bfr[ni] = *(bf16x8*)&Bt[(wn*64 + ni*16 + lr)*64 + kk + lk8];
#pragma unroll
      for (int mi = 0; mi < 4; mi++)
#pragma unroll
        for (int ni = 0; ni < 4; ni++)
          acc[mi][ni] = __builtin_amdgcn_mfma_f32_16x16x32_bf16(af[mi], bfr[ni], acc[mi][ni], 0, 0, 0);
    }
  }
  int orow = (lane >> 4) * 4, ocol = lane & 15;
#pragma unroll
  for (int mi = 0; mi < 4; mi++)
#pragma unroll
    for (int ni = 0; ni < 4; ni++){
      int row = m0 + wm*64 + mi*16 + orow;
      int col = n0 + wn*64 + ni*16 + ocol;
      long cidx = cbase + (long)row*ldc + col;
#pragma unroll
      for (int r = 0; r < 4; r++){
        float vv = acc[mi][ni][r];
        if (EPI == 2){
          float x = vv + bias[col];
          ((u16*)Cp)[cidx + (long)r*ldc] = f2bc(0.5f * x * (1.f + erff(x * 0.70710678118654752f)));
        }
        else if (EPI == 1) ((u16*)Cp)[cidx + (long)r*ldc] = f2bc(vv);
        else               ((float*)Cp)[cidx + (long)r*ldc] = vv;
      }
    }
}

// ---------------------------------------------------------------- fused attention
// Pass A: per (b,h,j-tile of 64): m_j, 1/Z_j over all i (masked). 4 waves x 16 j-rows.
// R9 proven form: batched register staging + 1-tile-ahead prefetch, reg-resident K.
// R14: + T1 XCD remap.  R15: + T5 setprio around the QK^T MFMA cluster.
template<int KD, bool MASK>
__global__ __launch_bounds__(256) void attn_passA(
    const u16* __restrict__ Kp, const u16* __restrict__ Qp, float* __restrict__ mz,
    int J, int kld, int qld,
    long kob, long koh, long qob, long qoh, int H, float scale, int mztot)
{
  constexpr int KP = KD + 8;
  constexpr int RCH = KD / 8;
  constexpr int QREG = KD / 16;            // u16x8 regs per thread for the 128-row Q tile
  __shared__ u16 Qt[128*KP];
  int bx, bh, bz;
  xcd_remap(gridDim.x, gridDim.y, gridDim.z, bx, bh, bz);
  int b = bh / H, h = bh % H;
  const u16* Kb = Kp + (long)b*kob + (long)h*koh;
  const u16* Qb = Qp + (long)b*qob + (long)h*qoh;
  int j0 = bx * 64;
  int tid = threadIdx.x, lane = tid & 63, w = tid >> 6;
  int lr = lane & 15, lk8 = (lane >> 4) * 8;
  bf16x8 ak[KD/32];
  {
    const u16* kr = &Kb[(long)(j0 + w*16 + lr)*kld];
#pragma unroll
    for (int kk = 0; kk < KD/32; kk++) ak[kk] = *(const bf16x8*)&kr[kk*32 + lk8];
  }
  float m_run[4], z_run[4];
#pragma unroll
  for (int r = 0; r < 4; r++){ m_run[r] = -3.0e38f; z_run[r] = 0.f; }
  f32x4 zz = {0.f,0.f,0.f,0.f};
  int itLo = 0;
  if (MASK){ int tt = j0 - 1151; itLo = tt > 0 ? (tt + 127)/128 : 0; }
  u16x8 qreg[QREG];
#pragma unroll
  for (int qq = 0; qq < QREG; qq++){
    int idx = tid + qq*256; int r = idx / RCH, c = (idx % RCH) * 8;
    qreg[qq] = *(const u16x8*)&Qb[(long)(itLo*128 + r)*qld + c];
  }
  for (int it = itLo; it < 8; it++){
    __syncthreads();                       // prior Qt reads done before overwrite
#pragma unroll
    for (int qq = 0; qq < QREG; qq++){
      int idx = tid + qq*256; int r = idx / RCH, c = (idx % RCH) * 8;
      *(u16x8*)&Qt[r*KP + c] = qreg[qq];
    }
    if (it + 1 < 8){
#pragma unroll
      for (int qq = 0; qq < QREG; qq++){
        int idx = tid + qq*256; int r = idx / RCH, c = (idx % RCH) * 8;
        qreg[qq] = *(const u16x8*)&Qb[(long)((it+1)*128 + r)*qld + c];
      }
    }
    __syncthreads();                       // Qt ready
    f32x4 acc[8];
#pragma unroll
    for (int ni = 0; ni < 8; ni++) acc[ni] = zz;
    __builtin_amdgcn_s_setprio(1);         // T5: favor this wave's compute phase
#pragma unroll
    for (int kk = 0; kk < KD; kk += 32){
      bf16x8 bq[8];
#pragma unroll
      for (int ni = 0; ni < 8; ni++) bq[ni] = *(bf16x8*)&Qt[(ni*16 + lr)*KP + kk + lk8];
#pragma unroll
      for (int ni = 0; ni < 8; ni++)
        acc[ni] = __builtin_amdgcn_mfma_f32_16x16x32_bf16(ak[kk/32], bq[ni], acc[ni], 0, 0, 0);
    }
    __builtin_amdgcn_s_setprio(0);
#pragma unroll
    for (int r = 0; r < 4; r++){
      int jg = j0 + w*16 + ((lane >> 4) << 2) + r;
      float sv[8]; float tm = -3.0e38f;
#pragma unroll
      for (int ni = 0; ni < 8; ni++){
        int ig = it*128 + ni*16 + (lane & 15);
        float s = acc[ni][r] * scale;
        bool val = (!MASK) || (ig >= jg - 1024);
        sv[ni] = val ? s : -3.0e38f;
        tm = fmaxf(tm, sv[ni]);
      }
#pragma unroll
      for (int off = 1; off < 16; off <<= 1) tm = fmaxf(tm, __shfl_xor(tm, off));
      float mn = fmaxf(m_run[r], tm);
      float zt = 0.f;
#pragma unroll
      for (int ni = 0; ni < 8; ni++)
        zt += (sv[ni] > -1.0e37f) ? __expf(sv[ni] - mn) : 0.f;
#pragma unroll
      for (int off = 1; off < 16; off <<= 1) zt += __shfl_xor(zt, off);
      z_run[r] = z_run[r] * __expf(m_run[r] - mn) + zt;
      m_run[r] = mn;
    }
  }
  if ((lane & 15) == 0){
#pragma unroll
    for (int r = 0; r < 4; r++){
      int jg = j0 + w*16 + ((lane >> 4) << 2) + r;
      mz[(long)bh*J + jg] = m_run[r];
      mz[(long)mztot + (long)bh*J + jg] = 1.f / z_run[r];
    }
  }
}

// Pass B: per (b,h,i-tile of 64, j-half). R9 proven body (KVBLK=128, batched register
// staging + 1-tile prefetch, reg-resident Q, LDS-staged K/V with K/P alias).
// R14: + T1 XCD remap; native (__bf16) RNE P-write.  R15: + T5 setprio around MFMA.
template<int KD, bool MASK>
__global__ __launch_bounds__(256) void attn_passB(
    const u16* __restrict__ Kp, const u16* __restrict__ Qp, const u16* __restrict__ Vtp,
    const float* __restrict__ mz, float* __restrict__ Op,
    int J, int kld, int qld, int vld, int oldd,
    long kob, long koh, long qob, long qoh, long vob, long voh, long oob, long ooh,
    int H, float scale, int mztot, int jtHalf, long opstride)
{
  constexpr int KP = KD + 8, PSTR = 140, VSTR = 136;
  constexpr int RCH = KD / 8;
  constexpr int KREG = KD / 16;            // u16x8 regs per thread for the 128-row K tile
  __shared__ u16 PK[128*KP];       // K tile (128 x KP) ; aliased by P tile (64 x PSTR)
  __shared__ u16 Vtt[64*VSTR];
  u16* Kt = PK;
  u16* Pt = PK;
  int bx, bh, jh;
  xcd_remap(gridDim.x, gridDim.y, gridDim.z, bx, bh, jh);
  int b = bh / H, h = bh % H;
  const u16* Kb = Kp + (long)b*kob + (long)h*koh;
  const u16* Qb = Qp + (long)b*qob + (long)h*qoh;
  const u16* Vb = Vtp + (long)b*vob + (long)h*voh;
  float* Ob = Op + (long)jh*opstride + (long)b*oob + (long)h*ooh;
  const float* mzm = mz + (long)bh*J;
  const float* mzz = mz + (long)mztot + (long)bh*J;
  int i0 = bx * 64;
  int tid = threadIdx.x, lane = tid & 63, w = tid >> 6;
  int lr = lane & 15, lk8 = (lane >> 4) * 8;
  // Q fragment in registers: wave's own 16 i-rows, reused across all j-tiles
  bf16x8 aq[KD/32];
  {
    const u16* qr = &Qb[(long)(i0 + w*16 + lr)*qld];
#pragma unroll
    for (int kk = 0; kk < KD/32; kk++) aq[kk] = *(const bf16x8*)&qr[kk*32 + lk8];
  }
  f32x4 acc_o[4];
  f32x4 zz = {0.f,0.f,0.f,0.f};
#pragma unroll
  for (int nd = 0; nd < 4; nd++) acc_o[nd] = zz;
  int lo = jh * jtHalf, hi = lo + jtHalf;
  if (MASK){ int lim = (i0 + 1087)/128 + 1; hi = hi < lim ? hi : lim; }
  if (lo < hi){
    u16x8 kreg[KREG];
    u16x8 vreg[4];
#pragma unroll
    for (int qq = 0; qq < KREG; qq++){
      int idx = tid + qq*256; int r = idx / RCH, c = (idx % RCH) * 8;
      kreg[qq] = *(const u16x8*)&Kb[(long)(lo*128 + r)*kld + c];
    }
#pragma unroll
    for (int qq = 0; qq < 4; qq++){
      int idx = tid + qq*256; int r = idx >> 4, c = (idx & 15) << 3;
      vreg[qq] = *(const u16x8*)&Vb[(long)r*vld + lo*128 + c];
    }
    for (int jt = lo; jt < hi; jt++){
      __syncthreads();                     // prior P/Vt reads done before restage
#pragma unroll
      for (int qq = 0; qq < KREG; qq++){
        int idx = tid + qq*256; int r = idx / RCH, c = (idx % RCH) * 8;
        *(u16x8*)&Kt[r*KP + c] = kreg[qq];
      }
#pragma unroll
      for (int qq = 0; qq < 4; qq++){
        int idx = tid + qq*256; int r = idx >> 4, c = (idx & 15) << 3;
        *(u16x8*)&Vtt[r*VSTR + c] = vreg[qq];
      }
      if (jt + 1 < hi){                    // prefetch next tile during this tile's compute
#pragma unroll
        for (int qq = 0; qq < KREG; qq++){
          int idx = tid + qq*256; int r = idx / RCH, c = (idx % RCH) * 8;
          kreg[qq] = *(const u16x8*)&Kb[(long)((jt+1)*128 + r)*kld + c];
        }
#pragma unroll
        for (int qq = 0; qq < 4; qq++){
          int idx = tid + qq*256; int r = idx >> 4, c = (idx & 15) << 3;
          vreg[qq] = *(const u16x8*)&Vb[(long)r*vld + (jt+1)*128 + c];
        }
      }
      __syncthreads();                     // K/V LDS ready
      float mjv[8], zjv[8];
#pragma unroll
      for (int ni = 0; ni < 8; ni++){      // issue before MFMA: latency hides under QK^T
        int jg = jt*128 + ni*16 + (lane & 15);
        mjv[ni] = mzm[jg]; zjv[ni] = mzz[jg];
      }
      // S tile: A = Q regs (own wave's 16 i-rows), B = K (128 j)
      f32x4 acc[8];
#pragma unroll
      for (int ni = 0; ni < 8; ni++) acc[ni] = zz;
      __builtin_amdgcn_s_setprio(1);       // T5
#pragma unroll
      for (int kk = 0; kk < KD; kk += 32){
        bf16x8 bk[8];
#pragma unroll
        for (int ni = 0; ni < 8; ni++) bk[ni] = *(bf16x8*)&Kt[(ni*16 + lr)*KP + kk + lk8];
#pragma unroll
        for (int ni = 0; ni < 8; ni++)
          acc[ni] = __builtin_amdgcn_mfma_f32_16x16x32_bf16(aq[kk/32], bk[ni], acc[ni], 0, 0, 0);
      }
      __builtin_amdgcn_s_setprio(0);
      __syncthreads();                     // K reads done before P overwrite (alias)
#pragma unroll
      for (int ni = 0; ni < 8; ni++){
        int jg = jt*128 + ni*16 + (lane & 15);
#pragma unroll
        for (int r = 0; r < 4; r++){
          int ig = i0 + w*16 + ((lane >> 4) << 2) + r;
          bool val = (!MASK) || (ig >= jg - 1024);
          float p = val ? __expf(acc[ni][r] * scale - mjv[ni]) * zjv[ni] : 0.f;
          Pt[(w*16 + ((lane >> 4) << 2) + r)*PSTR + ni*16 + (lane & 15)] = f2bc(p);
        }
      }
      // no barrier: P write->read is within-wave (own 16 rows), DS pipe is in-order
      // PV: A = P (own wave's 16 i-rows), B = Vt (64 d-rows)
      __builtin_amdgcn_s_setprio(1);       // T5
#pragma unroll
      for (int kk = 0; kk < 128; kk += 32){
        bf16x8 pa, vb[4];
        pa = *(bf16x8*)&Pt[(w*16 + lr)*PSTR + kk + lk8];
#pragma unroll
        for (int nd = 0; nd < 4; nd++) vb[nd] = *(bf16x8*)&Vtt[(nd*16 + lr)*VSTR + kk + lk8];
#pragma unroll
        for (int nd = 0; nd < 4; nd++)
          acc_o[nd] = __builtin_amdgcn_mfma_f32_16x16x32_bf16(pa, vb[nd], acc_o[nd], 0, 0, 0);
      }
      __builtin_amdgcn_s_setprio(0);
    }
  }
#pragma unroll
  for (int nd = 0; nd < 4; nd++)
#pragma unroll
    for (int r = 0; r < 4; r++){
      int ig = i0 + w*16 + ((lane >> 4) << 2) + r;
      int d = nd*16 + (lane & 15);
      Ob[(long)ig*oldd + d] = acc_o[nd][r];
    }
}

// ---------------------------------------------------------------- o = bf16(part0 + part1)
__global__ __launch_bounds__(256) void combine_o(const float* __restrict__ p, u16* __restrict__ o)
{
  const long PS = 2097152;
  long i = ((long)blockIdx.x*256 + threadIdx.x) * 4;
  const float* a = &p[i];
  const float* b = &p[i + PS];
  u16x4 r;
#pragma unroll
  for (int e = 0; e < 4; e++) r[e] = f2bc(a[e] + b[e]);
  *(u16x4*)&o[i] = r;
}

// ---------------------------------------------------------------- bf16 transpose dst[c,r]=src[r,c]
__global__ __launch_bounds__(256) void transpose_k(
    const u16* __restrict__ src, u16* __restrict__ dst,
    int lds_, int ldd, int Hh, long sob, long soh, long dob, long doh)
{
  __shared__ u16 tile[64*72];
  int z = blockIdx.z, b_ = z / Hh, h_ = z % Hh;
  const u16* S_ = src + (long)b_*sob + (long)h_*soh;
  u16* D_ = dst + (long)b_*dob + (long)h_*doh;
  int r0 = blockIdx.y * 64, c0 = blockIdx.x * 64;
  int tid = threadIdx.x;
  for (int idx = tid; idx < 512; idx += 256){
    int r = idx >> 3, c = (idx & 7) << 3;
    *(u16x8*)&tile[r*72 + c] = *(const u16x8*)&S_[(long)(r0 + r)*lds_ + c0 + c];
  }
  __syncthreads();
  for (int idx = tid; idx < 512; idx += 256){
    int c = idx >> 3, r = (idx & 7) << 3;
    u16x8 v;
#pragma unroll
    for (int e = 0; e < 8; e++) v[e] = tile[(r + e)*72 + c];
    *(u16x8*)&D_[(long)(c0 + c)*ldd + r0 + r] = v;
  }
}

// ---------------------------------------------------------------- fp32 src -> bf16 transposed dst
__global__ __launch_bounds__(256) void transpose_cvt_k(
    const float* __restrict__ src, u16* __restrict__ dst, int lds_, int ldd)
{
  __shared__ u16 tile[64*72];
  int r0 = blockIdx.y * 64, c0 = blockIdx.x * 64;
  int tid = threadIdx.x;
  for (int idx = tid; idx < 512; idx += 256){
    int r = idx >> 3, c = (idx & 7) << 3;
    const float* s = &src[(long)(r0 + r)*lds_ + c0 + c];
#pragma unroll
    for (int e = 0; e < 8; e++) tile[r*72 + c + e] = f2b(s[e]);
  }
  __syncthreads();
  for (int idx = tid; idx < 512; idx += 256){
    int c = idx >> 3, r = (idx & 7) << 3;
    u16x8 v;
#pragma unroll
    for (int e = 0; e < 8; e++) v[e] = tile[(r + e)*72 + c];
    *(u16x8*)&dst[(long)(c0 + c)*ldd + r0 + r] = v;
  }
}

// ---------------------------------------------------------------- flat fp32 -> bf16
__global__ __launch_bounds__(256) void cvt_k(const float* __restrict__ src, u16* __restrict__ dst)
{
  long i = ((long)blockIdx.x*256 + threadIdx.x) * 4;
  float4 v = *(const float4*)&src[i];
  u16x4 o; o[0] = f2b(v.x); o[1] = f2b(v.y); o[2] = f2b(v.z); o[3] = f2b(v.w);
  *(u16x4*)&dst[i] = o;
}

// ---------------------------------------------------------------- LayerNorm row=1024, fp32 in, bf16 out
__global__ __launch_bounds__(256) void ln_k(const float* __restrict__ src, const float* __restrict__ g,
                                            const float* __restrict__ be, u16* __restrict__ out)
{
  long base = (long)blockIdx.x * 1024;
  int tid = threadIdx.x;
  const float* s = src + base + tid*4;
  float v[4] = {s[0], s[1], s[2], s[3]};
  float s1 = v[0]+v[1]+v[2]+v[3];
  float s2 = v[0]*v[0]+v[1]*v[1]+v[2]*v[2]+v[3]*v[3];
  block_red2(s1, s2);
  float mu = s1 * (1.f/1024.f);
  float var = s2 * (1.f/1024.f) - mu*mu;
  float rs = rsqrtf(var + 1e-5f);
#pragma unroll
  for (int e = 0; e < 4; e++){
    int col = tid*4 + e;
    out[base + col] = f2b((v[e]-mu)*rs*g[col] + be[col]);
  }
}

// ---------------------------------------------------------------- out = resid + LN(sum4(go) + xn + bias)  (fp32 out)
__global__ __launch_bounds__(256) void add_ln_k(const float* __restrict__ go,
    const u16* __restrict__ xn, const float* __restrict__ bias,
    const float* __restrict__ g, const float* __restrict__ be,
    const float* __restrict__ resid, float* __restrict__ outp)
{
  const long PS = 2097152;
  long base = (long)blockIdx.x * 1024;
  int tid = threadIdx.x;
  float v[4];
#pragma unroll
  for (int e = 0; e < 4; e++){
    int col = tid*4 + e;
    long idx = base + col;
    v[e] = go[idx] + go[idx + PS] + go[idx + 2*PS] + go[idx + 3*PS] + b2f(xn[idx]) + bias[col];
  }
  float s1 = v[0]+v[1]+v[2]+v[3];
  float s2 = v[0]*v[0]+v[1]*v[1]+v[2]*v[2]+v[3]*v[3];
  block_red2(s1, s2);
  float mu = s1 * (1.f/1024.f);
  float var = s2 * (1.f/1024.f) - mu*mu;
  float rs = rsqrtf(var + 1e-5f);
#pragma unroll
  for (int e = 0; e < 4; e++){
    int col = tid*4 + e;
    outp[base + col] = resid[base + col] + (v[e]-mu)*rs*g[col] + be[col];
  }
}

// ---------------------------------------------------------------- QQ = [q+u | shifted(q+v)]  (B,S,H,128)
__global__ __launch_bounds__(256) void build_qq(const u16* __restrict__ q, const float* __restrict__ u,
                                                const float* __restrict__ v, u16* __restrict__ QQ)
{
  int bi = blockIdx.x;
  long qrow = (long)bi * 1024;
  long obase = (long)bi * 2048;
  int n = bi + 2;
  int bp = n / 1025, ip = n % 1025;
  long qsrc = ip ? ((long)(bp*1024 + ip - 1)) * 1024 : -1;
  for (int t = threadIdx.x; t < 2048; t += 256){
    int h = t >> 7, e = t & 127;
    float val;
    if (e < 64) val = b2f(q[qrow + h*64 + e]) + u[h*64 + e];
    else {
      int d = e - 64;
      val = (qsrc < 0) ? 0.f : b2f(q[qsrc + h*64 + d]) + v[h*64 + d];
    }
    QQ[obase + t] = f2b(val);
  }
}

// ---------------------------------------------------------------- BB = [k | pos_emb]  (B,St,H,128)
__global__ __launch_bounds__(256) void build_bb(const u16* __restrict__ kv, const float* __restrict__ pe,
                                                u16* __restrict__ BB)
{
  int bj = blockIdx.x;
  int j = bj & 2047;
  long kvrow = (long)bj * 2048;
  long obase = (long)bj * 2048;
  for (int t = threadIdx.x; t < 2048; t += 256){
    int h = t >> 7, e = t & 127;
    u16 val = (e < 64) ? kv[kvrow + h*64 + e] : f2b(pe[(long)j*1024 + h*64 + (e - 64)]);
    BB[obase + t] = val;
  }
}

// ---------------------------------------------------------------- out3 = out2 + sum4(f2) + b2  (fp32 out, float4)
__global__ __launch_bounds__(256) void final_k(const float* __restrict__ out2, const float* __restrict__ f2,
                                               const float* __restrict__ b2v, float* __restrict__ outp)
{
  const long PS = 2097152;
  long i = ((long)blockIdx.x*256 + threadIdx.x) * 4;
  float4 o2 = *(const float4*)&out2[i];
  float4 a0 = *(const float4*)&f2[i];
  float4 a1 = *(const float4*)&f2[i + PS];
  float4 a2 = *(const float4*)&f2[i + 2*PS];
  float4 a3 = *(const float4*)&f2[i + 3*PS];
  float4 bb = *(const float4*)&b2v[i & 1023];
  float4 r;
  r.x = o2.x + a0.x + a1.x + a2.x + a3.x + bb.x;
  r.y = o2.y + a0.y + a1.y + a2.y + a3.y + bb.y;
  r.z = o2.z + a0.z + a1.z + a2.z + a3.z + bb.z;
  r.w = o2.w + a0.w + a1.w + a2.w + a3.w + bb.w;
  *(float4*)&outp[i] = r;
}

// ================================================================ host
extern "C" void kernel_launch(void* const* d_in, const int* in_sizes, int n_in,
                              void* d_out, int out_size, void* d_ws, size_t ws_size,
                              hipStream_t stream)
{
  (void)in_sizes; (void)n_in; (void)out_size; (void)ws_size;
  // B=2 S=1024 M=1024 St=2048 D=DI=1024 H=16 DH=64 DFF=4096 ; ALL inputs/output fp32
  const float* X    = (const float*)d_in[0];
  const float* ENC  = (const float*)d_in[1];
  const float* PE   = (const float*)d_in[2];
  const float* Uu   = (const float*)d_in[3];
  const float* Vv   = (const float*)d_in[4];
  const float* MEM  = (const float*)d_in[5];
  const float* WQM  = (const float*)d_in[7];
  const float* WKVM = (const float*)d_in[8];
  const float* FCWM = (const float*)d_in[9];
  const float* FCBM = (const float*)d_in[10];
  const float* LNMG = (const float*)d_in[11];
  const float* LNMB = (const float*)d_in[12];
  const float* WQC  = (const float*)d_in[13];
  const float* WKVC = (const float*)d_in[14];
  const float* FCWC = (const float*)d_in[15];
  const float* FCBC = (const float*)d_in[16];
  const float* LNCG = (const float*)d_in[17];
  const float* LNCB = (const float*)d_in[18];
  const float* W1   = (const float*)d_in[19];
  const float* B1   = (const float*)d_in[20];
  const float* W2   = (const float*)d_in[21];
  const float* B2   = (const float*)d_in[22];
  const float* LN1G = (const float*)d_in[23];
  const float* LN1B = (const float*)d_in[24];
  const float* LN2G = (const float*)d_in[25];
  const float* LN2B = (const float*)d_in[26];
  const float* LN3G = (const float*)d_in[27];
  const float* LN3B = (const float*)d_in[28];
  float* OUT = (float*)d_out;
  char* W = (char*)d_ws;
  const size_t MB = 1ull << 20;

  // ---- layout, peak 122 MB (same as R9)
  u16*   wT_a  = (u16*)(W + 0*MB);
  u16*   wT_b  = (u16*)(W + 2*MB);
  u16*   wT_c  = (u16*)(W + 6*MB);
  u16*   w1T   = (u16*)(W + 0*MB);
  u16*   xn1   = (u16*)(W + 8*MB);
  u16*   q     = (u16*)(W + 12*MB);
  u16*   o_b   = (u16*)(W + 12*MB);
  u16*   kv    = (u16*)(W + 16*MB);
  float* outb  = (float*)(W + 24*MB);
  u16*   QQ    = (u16*)(W + 32*MB);
  u16*   xn2   = (u16*)(W + 32*MB);
  u16*   qc    = (u16*)(W + 36*MB);
  u16*   BB    = (u16*)(W + 40*MB);
  u16*   kvc   = (u16*)(W + 40*MB);
  u16*   Vtc   = (u16*)(W + 48*MB);
  u16*   oc    = (u16*)(W + 52*MB);
  u16*   Vt    = (u16*)(W + 56*MB);
  u16*   w2T   = (u16*)(W + 56*MB);
  float* mzb   = (float*)(W + 64*MB);
  u16*   memb  = (u16*)(W + 68*MB);
  u16*   encb  = (u16*)(W + 68*MB);
  float* opart = (float*)(W + 66*MB);    // 2 partials x 8 MB (dead before ofc is written)
  float* ofc   = (float*)(W + 66*MB);    // 4 partials x 8 MB
  float* f1    = (float*)(W + 66*MB);
  float* f2    = (float*)(W + 66*MB);    // 4 partials x 8 MB
  u16*   h1    = (u16*)(W + 98*MB);
  float* out2b = (float*)(W + 114*MB);

  // ================= MHA (Transformer-XL relative attention) =================
  transpose_cvt_k<<<dim3(16,16),256,0,stream>>>(WQM,  wT_a, 1024,1024);
  transpose_cvt_k<<<dim3(32,16),256,0,stream>>>(WKVM, wT_b, 2048,1024);
  transpose_cvt_k<<<dim3(16,16),256,0,stream>>>(FCWM, wT_c, 1024,1024);
  cvt_k<<<2048,256,0,stream>>>(MEM, memb);
  ln_k<<<2048,256,0,stream>>>(X, LN1G, LN1B, xn1);
  gemm_bt<2,2,1><<<dim3(8,16,1),256,0,stream>>>(xn1, nullptr, wT_a, q, nullptr, 1024, 1024,1024,1024, 1, 0,0,0,0,0,0);
  // merged kv GEMM: z = (b<<1)|src ; h_ = src selects memb/xn1 ; coh = src row offset
  gemm_bt<2,2,1><<<dim3(16,8,4),256,0,stream>>>(memb, xn1, wT_b, kv, nullptr, 1024, 1024,1024,2048, 2,
      1048576,0, 0,0, 4194304,2097152);
  build_qq<<<2048,256,0,stream>>>(q, Uu, Vv, QQ);
  build_bb<<<4096,256,0,stream>>>(kv, PE, BB);
  transpose_k<<<dim3(1,32,32),256,0,stream>>>(kv + 1024, Vt, 2048, 2048, 16,
      4194304,64, 2097152,131072);
  attn_passA<128,true><<<dim3(32,32),256,0,stream>>>(BB, QQ, mzb, 2048, 2048, 2048,
      4194304,128, 2097152,128, 16, 0.125f, 65536);
  attn_passB<128,true><<<dim3(16,32,2),256,0,stream>>>(BB, QQ, Vt, mzb, opart, 2048,
      2048,2048,2048,1024, 4194304,128, 2097152,128, 2097152,131072, 1048576,64, 16, 0.125f, 65536,
      8, 2097152);
  combine_o<<<2048,256,0,stream>>>(opart, o_b);
  gemm_bt<2,2,0><<<dim3(8,16,4),256,0,stream>>>(o_b, nullptr, wT_c, ofc, nullptr, 256, 1024,1024,1024, 4,
      0,256, 0,256, 0,2097152);
  add_ln_k<<<2048,256,0,stream>>>(ofc, xn1, FCBM, LNMG, LNMB, X, outb);

  // ================= cross attention =================
  transpose_cvt_k<<<dim3(16,16),256,0,stream>>>(WQC,  wT_a, 1024,1024);
  transpose_cvt_k<<<dim3(32,16),256,0,stream>>>(WKVC, wT_b, 2048,1024);
  transpose_cvt_k<<<dim3(16,16),256,0,stream>>>(FCWC, wT_c, 1024,1024);
  cvt_k<<<2048,256,0,stream>>>(ENC, encb);
  ln_k<<<2048,256,0,stream>>>(outb, LN2G, LN2B, xn2);
  gemm_bt<2,2,1><<<dim3(8,16,1),256,0,stream>>>(xn2, nullptr, wT_a, qc, nullptr, 1024, 1024,1024,1024, 1, 0,0,0,0,0,0);
  gemm_bt<2,2,1><<<dim3(16,16,1),256,0,stream>>>(encb, nullptr, wT_b, kvc, nullptr, 1024, 1024,1024,2048, 1, 0,0,0,0,0,0);
  transpose_k<<<dim3(1,16,32),256,0,stream>>>(kvc + 1024, Vtc, 2048, 1024, 16,
      2097152,64, 1048576,65536);
  attn_passA<64,false><<<dim3(16,32),256,0,stream>>>(kvc, qc, mzb, 1024, 2048, 1024,
      2097152,64, 1048576,64, 16, 0.125f, 32768);
  attn_passB<64,false><<<dim3(16,32,2),256,0,stream>>>(kvc, qc, Vtc, mzb, opart, 1024,
      2048,1024,1024,1024, 2097152,64, 1048576,64, 1048576,65536, 1048576,64, 16, 0.125f, 32768,
      4, 2097152);
  combine_o<<<2048,256,0,stream>>>(opart, oc);
  gemm_bt<2,2,0><<<dim3(8,16,4),256,0,stream>>>(oc, nullptr, wT_c, ofc, nullptr, 256, 1024,1024,1024, 4,
      0,256, 0,256, 0,2097152);
  add_ln_k<<<2048,256,0,stream>>>(ofc, xn2, FCBC, LNCG, LNCB, outb, out2b);

  // ================= FFN =================
  transpose_cvt_k<<<dim3(64,16),256,0,stream>>>(W1, w1T, 4096,1024);
  transpose_cvt_k<<<dim3(16,64),256,0,stream>>>(W2, w2T, 1024,4096);
  ln_k<<<2048,256,0,stream>>>(out2b, LN3G, LN3B, xn2);
  gemm_bt<2,2,2><<<dim3(32,16,1),256,0,stream>>>(xn2, nullptr, w1T, h1, B1, 1024, 1024,1024,4096, 1, 0,0,0,0,0,0);
  gemm_bt<2,2,0><<<dim3(8,16,4),256,0,stream>>>(h1, nullptr, w2T, f2, nullptr, 1024, 4096,4096,1024, 4,
      0,1024, 0,1024, 0,2097152);
  final_k<<<2048,256,0,stream>>>(out2b, f2, B2, OUT);
}

// Round 13
// 647.715 us; speedup vs baseline: 1.0326x; 1.0024x over previous
//
#include <hip/hip_runtime.h>

typedef unsigned short u16;
typedef __attribute__((ext_vector_type(4))) unsigned short u16x4;
typedef __attribute__((ext_vector_type(8))) unsigned short u16x8;
typedef __attribute__((ext_vector_type(8))) __bf16 bf16x8;
typedef __attribute__((ext_vector_type(4))) float f32x4;

#define DEV __device__ __forceinline__

DEV float b2f(u16 u){ union{ unsigned int i; float f; } x; x.i = ((unsigned int)u) << 16; return x.f; }
DEV u16 f2b(float f){ unsigned int x = __float_as_uint(f); return (u16)((x + 0x7fffu + ((x >> 16) & 1u)) >> 16); }
DEV u16 f2bc(float f){ __bf16 h = (__bf16)f; return *(u16*)&h; }   // native RNE cvt (1 VALU op)

// T1: XCD-aware block remap (attention form). Blocks sharing `bh` cluster on one XCD.
// R14 measured: FETCH 99MB -> 16.7MB (6x), passB 84 -> 78us.
DEV void xcd_remap(int nx, int nbh, int nz, int& x, int& bh, int& z){
  int hwid = blockIdx.x + nx*(blockIdx.y + nbh*blockIdx.z);
  int xcd = hwid & 7, slot = hwid >> 3;
  int bhper = nbh >> 3;
  int pg = nx*nz;
  bh = xcd*bhper + slot/pg;
  int rem = slot % pg;
  z = rem / nx;
  x = rem % nx;
}

// R17: T1 for GEMMs — each XCD owns a contiguous chunk of the grid with x (n-dim)
// slowest -> per-XCD B-slice + A panel ~L2-resident. Measured R17: 663 -> 649us.
// Bijective when total%8==0 (all call sites); runtime fallback otherwise.
DEV void gemm_remap(int& bx, int& by, int& bz){
  int nx = gridDim.x, ny = gridDim.y, nz = gridDim.z;
  int n = nx*ny*nz;
  if (n & 7){ bx = blockIdx.x; by = blockIdx.y; bz = blockIdx.z; return; }
  int id = blockIdx.x + nx*(blockIdx.y + ny*blockIdx.z);
  int chunk = n >> 3;
  int nid = (id & 7)*chunk + (id >> 3);
  int yz = ny*nz;
  bx = nid / yz;
  int rem = nid % yz;
  by = rem / nz;
  bz = rem % nz;
}

// ---------------------------------------------------------------- block reduce (256 thr)
DEV void block_red2(float& s, float& q){
#pragma unroll
  for (int off = 32; off; off >>= 1){ s += __shfl_down(s, off); q += __shfl_down(q, off); }
  __shared__ float sh1[4], sh2[4];
  int lane = threadIdx.x & 63, w = threadIdx.x >> 6;
  if (lane == 0){ sh1[w] = s; sh2[w] = q; }
  __syncthreads();
  s = sh1[0] + sh1[1] + sh1[2] + sh1[3];
  q = sh2[0] + sh2[1] + sh2[2] + sh2[3];
}

// ---------------------------------------------------------------- GEMM  C = A[M,K] * B[N,K]^T
// m97 recipe: async global->LDS (width 16), unpadded lane-contiguous LDS tiles.
// EPI: 0 = fp32 store, 1 = bf16 store, 2 = bf16 gelu(acc + bias[col]) store.
// A2: twin-A mode for the merged kv GEMM — h_ selects A (h_=0) vs A2 (h_=1).
// K-split pattern (R18, proven on o_b proj): z = K-slice, aoh/boh = K-offset,
// coh = fp32 partial-plane stride; combine_o sums the planes.
template<int WM, int WN, int EPI>
__global__ __launch_bounds__(WM*WN*64) void gemm_bt(
    const u16* __restrict__ A, const u16* __restrict__ A2,
    const u16* __restrict__ Bm, void* __restrict__ Cp,
    const float* __restrict__ bias,
    int K, int lda, int ldb, int ldc, int Hh,
    long aob, long aoh, long bob, long boh, long cob, long coh)
{
  constexpr int BM = WM*64, BN = WN*64, BK = 64, NW = WM*WN;
  __shared__ u16 At[BM*64];
  __shared__ u16 Bt[BN*64];
  int gx, gy, gz;
  gemm_remap(gx, gy, gz);
  int b_ = gz / Hh, h_ = gz % Hh;
  const u16* Abase = (A2 && h_) ? A2 : A;
  const u16* Ab = Abase + (long)b_*aob + (A2 ? 0 : (long)h_*aoh);
  const u16* Bb = Bm + (long)b_*bob + (long)h_*boh;
  long cbase = (long)b_*cob + (long)h_*coh;
  int m0 = gy * BM, n0 = gx * BN;
  int tid = threadIdx.x, lane = tid & 63, wv = tid >> 6;
  int wm = wv / WN, wn = wv % WN;
  f32x4 acc[4][4];
  f32x4 z4 = {0.f, 0.f, 0.f, 0.f};
#pragma unroll
  for (int a = 0; a < 4; a++)
#pragma unroll
    for (int b = 0; b < 4; b++) acc[a][b] = z4;
  int lr = lane & 15, lk8 = (lane >> 4) * 8;
  int rq = lane >> 3, cq = (lane & 7) << 3;      // lane -> (row-in-8, col-16B) of one inst
  for (int k0 = 0; k0 < K; k0 += BK){
    __syncthreads();                             // prev MFMA reads done before overwrite
#pragma unroll
    for (int q = wv; q < BM/8; q += NW){
      const u16* g = &Ab[(long)(m0 + q*8 + rq)*lda + k0 + cq];
      __builtin_amdgcn_global_load_lds((const __attribute__((address_space(1))) void*)g,
          (__attribute__((address_space(3))) void*)&At[q*512], 16, 0, 0);
    }
#pragma unroll
    for (int q = wv; q < BN/8; q += NW){
      const u16* g = &Bb[(long)(n0 + q*8 + rq)*ldb + k0 + cq];
      __builtin_amdgcn_global_load_lds((const __attribute__((address_space(1))) void*)g,
          (__attribute__((address_space(3))) void*)&Bt[q*512], 16, 0, 0);
    }
    __syncthreads();                             // drains vmcnt (loads landed in LDS)
#pragma unroll
    for (int kk = 0; kk < BK; kk += 32){
      bf16x8 af[4], bfr[4];
#pragma unroll
      for (int mi = 0; mi < 4; mi++) af[mi]  = *(bf16x8*)&At[(wm*64 + mi*16 + lr)*64 + kk + lk8];
#pragma unroll
      for (int ni = 0; ni < 4; ni++) bfr[ni] = *(bf16x8*)&Bt[(wn*64 + ni*16 + lr)*64 + kk + lk8];
#pragma unroll
      for (int mi = 0; mi < 4; mi++)
#pragma unroll
        for (int ni = 0; ni < 4; ni++)
          acc[mi][ni] = __builtin_amdgcn_mfma_f32_16x16x32_bf16(af[mi], bfr[ni], acc[mi][ni], 0, 0, 0);
    }
  }
  int orow = (lane >> 4) * 4, ocol = lane & 15;
#pragma unroll
  for (int mi = 0; mi < 4; mi++)
#pragma unroll
    for (int ni = 0; ni < 4; ni++){
      int row = m0 + wm*64 + mi*16 + orow;
      int col = n0 + wn*64 + ni*16 + ocol;
      long cidx = cbase + (long)row*ldc + col;
#pragma unroll
      for (int r = 0; r < 4; r++){
        float vv = acc[mi][ni][r];
        if (EPI == 2){
          float x = vv + bias[col];
          ((u16*)Cp)[cidx + (long)r*ldc] = f2bc(0.5f * x * (1.f + erff(x * 0.70710678118654752f)));
        }
        else if (EPI == 1) ((u16*)Cp)[cidx + (long)r*ldc] = f2bc(vv);
        else               ((float*)Cp)[cidx + (long)r*ldc] = vv;
      }
    }
}

// ---------------------------------------------------------------- fused attention
// Pass A: per (b,h,j-tile of 64): m_j, 1/Z_j over all i (masked). 4 waves x 16 j-rows.
// R9 proven form: batched register staging + 1-tile-ahead prefetch, reg-resident K.
// R14: + T1 XCD remap.  R15: + T5 setprio around the QK^T MFMA cluster.
template<int KD, bool MASK>
__global__ __launch_bounds__(256) void attn_passA(
    const u16* __restrict__ Kp, const u16* __restrict__ Qp, float* __restrict__ mz,
    int J, int kld, int qld,
    long kob, long koh, long qob, long qoh, int H, float scale, int mztot)
{
  constexpr int KP = KD + 8;
  constexpr int RCH = KD / 8;
  constexpr int QREG = KD / 16;            // u16x8 regs per thread for the 128-row Q tile
  __shared__ u16 Qt[128*KP];
  int bx, bh, bz;
  xcd_remap(gridDim.x, gridDim.y, gridDim.z, bx, bh, bz);
  int b = bh / H, h = bh % H;
  const u16* Kb = Kp + (long)b*kob + (long)h*koh;
  const u16* Qb = Qp + (long)b*qob + (long)h*qoh;
  int j0 = bx * 64;
  int tid = threadIdx.x, lane = tid & 63, w = tid >> 6;
  int lr = lane & 15, lk8 = (lane >> 4) * 8;
  bf16x8 ak[KD/32];
  {
    const u16* kr = &Kb[(long)(j0 + w*16 + lr)*kld];
#pragma unroll
    for (int kk = 0; kk < KD/32; kk++) ak[kk] = *(const bf16x8*)&kr[kk*32 + lk8];
  }
  float m_run[4], z_run[4];
#pragma unroll
  for (int r = 0; r < 4; r++){ m_run[r] = -3.0e38f; z_run[r] = 0.f; }
  f32x4 zz = {0.f,0.f,0.f,0.f};
  int itLo = 0;
  if (MASK){ int tt = j0 - 1151; itLo = tt > 0 ? (tt + 127)/128 : 0; }
  u16x8 qreg[QREG];
#pragma unroll
  for (int qq = 0; qq < QREG; qq++){
    int idx = tid + qq*256; int r = idx / RCH, c = (idx % RCH) * 8;
    qreg[qq] = *(const u16x8*)&Qb[(long)(itLo*128 + r)*qld + c];
  }
  for (int it = itLo; it < 8; it++){
    __syncthreads();                       // prior Qt reads done before overwrite
#pragma unroll
    for (int qq = 0; qq < QREG; qq++){
      int idx = tid + qq*256; int r = idx / RCH, c = (idx % RCH) * 8;
      *(u16x8*)&Qt[r*KP + c] = qreg[qq];
    }
    if (it + 1 < 8){
#pragma unroll
      for (int qq = 0; qq < QREG; qq++){
        int idx = tid + qq*256; int r = idx / RCH, c = (idx % RCH) * 8;
        qreg[qq] = *(const u16x8*)&Qb[(long)((it+1)*128 + r)*qld + c];
      }
    }
    __syncthreads();                       // Qt ready
    f32x4 acc[8];
#pragma unroll
    for (int ni = 0; ni < 8; ni++) acc[ni] = zz;
    __builtin_amdgcn_s_setprio(1);         // T5: favor this wave's compute phase
#pragma unroll
    for (int kk = 0; kk < KD; kk += 32){
      bf16x8 bq[8];
#pragma unroll
      for (int ni = 0; ni < 8; ni++) bq[ni] = *(bf16x8*)&Qt[(ni*16 + lr)*KP + kk + lk8];
#pragma unroll
      for (int ni = 0; ni < 8; ni++)
        acc[ni] = __builtin_amdgcn_mfma_f32_16x16x32_bf16(ak[kk/32], bq[ni], acc[ni], 0, 0, 0);
    }
    __builtin_amdgcn_s_setprio(0);
#pragma unroll
    for (int r = 0; r < 4; r++){
      int jg = j0 + w*16 + ((lane >> 4) << 2) + r;
      float sv[8]; float tm = -3.0e38f;
#pragma unroll
      for (int ni = 0; ni < 8; ni++){
        int ig = it*128 + ni*16 + (lane & 15);
        float s = acc[ni][r] * scale;
        bool val = (!MASK) || (ig >= jg - 1024);
        sv[ni] = val ? s : -3.0e38f;
        tm = fmaxf(tm, sv[ni]);
      }
#pragma unroll
      for (int off = 1; off < 16; off <<= 1) tm = fmaxf(tm, __shfl_xor(tm, off));
      float mn = fmaxf(m_run[r], tm);
      float zt = 0.f;
#pragma unroll
      for (int ni = 0; ni < 8; ni++)
        zt += (sv[ni] > -1.0e37f) ? __expf(sv[ni] - mn) : 0.f;
#pragma unroll
      for (int off = 1; off < 16; off <<= 1) zt += __shfl_xor(zt, off);
      z_run[r] = z_run[r] * __expf(m_run[r] - mn) + zt;
      m_run[r] = mn;
    }
  }
  if ((lane & 15) == 0){
#pragma unroll
    for (int r = 0; r < 4; r++){
      int jg = j0 + w*16 + ((lane >> 4) << 2) + r;
      mz[(long)bh*J + jg] = m_run[r];
      mz[(long)mztot + (long)bh*J + jg] = 1.f / z_run[r];
    }
  }
}

// Pass B: per (b,h,i-tile of 64, j-half). R9 proven body (KVBLK=128, batched register
// staging + 1-tile prefetch, reg-resident Q, LDS-staged K/V with K/P alias).
// R14: + T1 XCD remap; native (__bf16) RNE P-write.  R15: + T5 setprio around MFMA.
template<int KD, bool MASK>
__global__ __launch_bounds__(256) void attn_passB(
    const u16* __restrict__ Kp, const u16* __restrict__ Qp, const u16* __restrict__ Vtp,
    const float* __restrict__ mz, float* __restrict__ Op,
    int J, int kld, int qld, int vld, int oldd,
    long kob, long koh, long qob, long qoh, long vob, long voh, long oob, long ooh,
    int H, float scale, int mztot, int jtHalf, long opstride)
{
  constexpr int KP = KD + 8, PSTR = 140, VSTR = 136;
  constexpr int RCH = KD / 8;
  constexpr int KREG = KD / 16;            // u16x8 regs per thread for the 128-row K tile
  __shared__ u16 PK[128*KP];       // K tile (128 x KP) ; aliased by P tile (64 x PSTR)
  __shared__ u16 Vtt[64*VSTR];
  u16* Kt = PK;
  u16* Pt = PK;
  int bx, bh, jh;
  xcd_remap(gridDim.x, gridDim.y, gridDim.z, bx, bh, jh);
  int b = bh / H, h = bh % H;
  const u16* Kb = Kp + (long)b*kob + (long)h*koh;
  const u16* Qb = Qp + (long)b*qob + (long)h*qoh;
  const u16* Vb = Vtp + (long)b*vob + (long)h*voh;
  float* Ob = Op + (long)jh*opstride + (long)b*oob + (long)h*ooh;
  const float* mzm = mz + (long)bh*J;
  const float* mzz = mz + (long)mztot + (long)bh*J;
  int i0 = bx * 64;
  int tid = threadIdx.x, lane = tid & 63, w = tid >> 6;
  int lr = lane & 15, lk8 = (lane >> 4) * 8;
  // Q fragment in registers: wave's own 16 i-rows, reused across all j-tiles
  bf16x8 aq[KD/32];
  {
    const u16* qr = &Qb[(long)(i0 + w*16 + lr)*qld];
#pragma unroll
    for (int kk = 0; kk < KD/32; kk++) aq[kk] = *(const bf16x8*)&qr[kk*32 + lk8];
  }
  f32x4 acc_o[4];
  f32x4 zz = {0.f,0.f,0.f,0.f};
#pragma unroll
  for (int nd = 0; nd < 4; nd++) acc_o[nd] = zz;
  int lo = jh * jtHalf, hi = lo + jtHalf;
  if (MASK){ int lim = (i0 + 1087)/128 + 1; hi = hi < lim ? hi : lim; }
  if (lo < hi){
    u16x8 kreg[KREG];
    u16x8 vreg[4];
#pragma unroll
    for (int qq = 0; qq < KREG; qq++){
      int idx = tid + qq*256; int r = idx / RCH, c = (idx % RCH) * 8;
      kreg[qq] = *(const u16x8*)&Kb[(long)(lo*128 + r)*kld + c];
    }
#pragma unroll
    for (int qq = 0; qq < 4; qq++){
      int idx = tid + qq*256; int r = idx >> 4, c = (idx & 15) << 3;
      vreg[qq] = *(const u16x8*)&Vb[(long)r*vld + lo*128 + c];
    }
    for (int jt = lo; jt < hi; jt++){
      __syncthreads();                     // prior P/Vt reads done before restage
#pragma unroll
      for (int qq = 0; qq < KREG; qq++){
        int idx = tid + qq*256; int r = idx / RCH, c = (idx % RCH) * 8;
        *(u16x8*)&Kt[r*KP + c] = kreg[qq];
      }
#pragma unroll
      for (int qq = 0; qq < 4; qq++){
        int idx = tid + qq*256; int r = idx >> 4, c = (idx & 15) << 3;
        *(u16x8*)&Vtt[r*VSTR + c] = vreg[qq];
      }
      if (jt + 1 < hi){                    // prefetch next tile during this tile's compute
#pragma unroll
        for (int qq = 0; qq < KREG; qq++){
          int idx = tid + qq*256; int r = idx / RCH, c = (idx % RCH) * 8;
          kreg[qq] = *(const u16x8*)&Kb[(long)((jt+1)*128 + r)*kld + c];
        }
#pragma unroll
        for (int qq = 0; qq < 4; qq++){
          int idx = tid + qq*256; int r = idx >> 4, c = (idx & 15) << 3;
          vreg[qq] = *(const u16x8*)&Vb[(long)r*vld + (jt+1)*128 + c];
        }
      }
      __syncthreads();                     // K/V LDS ready
      float mjv[8], zjv[8];
#pragma unroll
      for (int ni = 0; ni < 8; ni++){      // issue before MFMA: latency hides under QK^T
        int jg = jt*128 + ni*16 + (lane & 15);
        mjv[ni] = mzm[jg]; zjv[ni] = mzz[jg];
      }
      // S tile: A = Q regs (own wave's 16 i-rows), B = K (128 j)
      f32x4 acc[8];
#pragma unroll
      for (int ni = 0; ni < 8; ni++) acc[ni] = zz;
      __builtin_amdgcn_s_setprio(1);       // T5
#pragma unroll
      for (int kk = 0; kk < KD; kk += 32){
        bf16x8 bk[8];
#pragma unroll
        for (int ni = 0; ni < 8; ni++) bk[ni] = *(bf16x8*)&Kt[(ni*16 + lr)*KP + kk + lk8];
#pragma unroll
        for (int ni = 0; ni < 8; ni++)
          acc[ni] = __builtin_amdgcn_mfma_f32_16x16x32_bf16(aq[kk/32], bk[ni], acc[ni], 0, 0, 0);
      }
      __builtin_amdgcn_s_setprio(0);
      __syncthreads();                     // K reads done before P overwrite (alias)
#pragma unroll
      for (int ni = 0; ni < 8; ni++){
        int jg = jt*128 + ni*16 + (lane & 15);
#pragma unroll
        for (int r = 0; r < 4; r++){
          int ig = i0 + w*16 + ((lane >> 4) << 2) + r;
          bool val = (!MASK) || (ig >= jg - 1024);
          float p = val ? __expf(acc[ni][r] * scale - mjv[ni]) * zjv[ni] : 0.f;
          Pt[(w*16 + ((lane >> 4) << 2) + r)*PSTR + ni*16 + (lane & 15)] = f2bc(p);
        }
      }
      // no barrier: P write->read is within-wave (own 16 rows), DS pipe is in-order
      // PV: A = P (own wave's 16 i-rows), B = Vt (64 d-rows)
      __builtin_amdgcn_s_setprio(1);       // T5
#pragma unroll
      for (int kk = 0; kk < 128; kk += 32){
        bf16x8 pa, vb[4];
        pa = *(bf16x8*)&Pt[(w*16 + lr)*PSTR + kk + lk8];
#pragma unroll
        for (int nd = 0; nd < 4; nd++) vb[nd] = *(bf16x8*)&Vtt[(nd*16 + lr)*VSTR + kk + lk8];
#pragma unroll
        for (int nd = 0; nd < 4; nd++)
          acc_o[nd] = __builtin_amdgcn_mfma_f32_16x16x32_bf16(pa, vb[nd], acc_o[nd], 0, 0, 0);
      }
      __builtin_amdgcn_s_setprio(0);
    }
  }
#pragma unroll
  for (int nd = 0; nd < 4; nd++)
#pragma unroll
    for (int r = 0; r < 4; r++){
      int ig = i0 + w*16 + ((lane >> 4) << 2) + r;
      int d = nd*16 + (lane & 15);
      Ob[(long)ig*oldd + d] = acc_o[nd][r];
    }
}

// ---------------------------------------------------------------- o = bf16(sum of NP partial planes)
template<int NP>
__global__ __launch_bounds__(256) void combine_o(const float* __restrict__ p, u16* __restrict__ o)
{
  const long PS = 2097152;
  long i = ((long)blockIdx.x*256 + threadIdx.x) * 4;
  u16x4 r;
#pragma unroll
  for (int e = 0; e < 4; e++){
    float a = p[i + e];
#pragma unroll
    for (int q = 1; q < NP; q++) a += p[i + e + (long)q*PS];
    r[e] = f2bc(a);
  }
  *(u16x4*)&o[i] = r;
}

// ---------------------------------------------------------------- bf16 transpose dst[c,r]=src[r,c]
__global__ __launch_bounds__(256) void transpose_k(
    const u16* __restrict__ src, u16* __restrict__ dst,
    int lds_, int ldd, int Hh, long sob, long soh, long dob, long doh)
{
  __shared__ u16 tile[64*72];
  int z = blockIdx.z, b_ = z / Hh, h_ = z % Hh;
  const u16* S_ = src + (long)b_*sob + (long)h_*soh;
  u16* D_ = dst + (long)b_*dob + (long)h_*doh;
  int r0 = blockIdx.y * 64, c0 = blockIdx.x * 64;
  int tid = threadIdx.x;
  for (int idx = tid; idx < 512; idx += 256){
    int r = idx >> 3, c = (idx & 7) << 3;
    *(u16x8*)&tile[r*72 + c] = *(const u16x8*)&S_[(long)(r0 + r)*lds_ + c0 + c];
  }
  __syncthreads();
  for (int idx = tid; idx < 512; idx += 256){
    int c = idx >> 3, r = (idx & 7) << 3;
    u16x8 v;
#pragma unroll
    for (int e = 0; e < 8; e++) v[e] = tile[(r + e)*72 + c];
    *(u16x8*)&D_[(long)(c0 + c)*ldd + r0 + r] = v;
  }
}

// ---------------------------------------------------------------- fp32 src -> bf16 transposed dst
__global__ __launch_bounds__(256) void transpose_cvt_k(
    const float* __restrict__ src, u16* __restrict__ dst, int lds_, int ldd)
{
  __shared__ u16 tile[64*72];
  int r0 = blockIdx.y * 64, c0 = blockIdx.x * 64;
  int tid = threadIdx.x;
  for (int idx = tid; idx < 512; idx += 256){
    int r = idx >> 3, c = (idx & 7) << 3;
    const float* s = &src[(long)(r0 + r)*lds_ + c0 + c];
#pragma unroll
    for (int e = 0; e < 8; e++) tile[r*72 + c + e] = f2b(s[e]);
  }
  __syncthreads();
  for (int idx = tid; idx < 512; idx += 256){
    int c = idx >> 3, r = (idx & 7) << 3;
    u16x8 v;
#pragma unroll
    for (int e = 0; e < 8; e++) v[e] = tile[(r + e)*72 + c];
    *(u16x8*)&dst[(long)(c0 + c)*ldd + r0 + r] = v;
  }
}

// ---------------------------------------------------------------- flat fp32 -> bf16
__global__ __launch_bounds__(256) void cvt_k(const float* __restrict__ src, u16* __restrict__ dst)
{
  long i = ((long)blockIdx.x*256 + threadIdx.x) * 4;
  float4 v = *(const float4*)&src[i];
  u16x4 o; o[0] = f2b(v.x); o[1] = f2b(v.y); o[2] = f2b(v.z); o[3] = f2b(v.w);
  *(u16x4*)&dst[i] = o;
}

// ---------------------------------------------------------------- LayerNorm row=1024, fp32 in, bf16 out
__global__ __launch_bounds__(256) void ln_k(const float* __restrict__ src, const float* __restrict__ g,
                                            const float* __restrict__ be, u16* __restrict__ out)
{
  long base = (long)blockIdx.x * 1024;
  int tid = threadIdx.x;
  const float* s = src + base + tid*4;
  float v[4] = {s[0], s[1], s[2], s[3]};
  float s1 = v[0]+v[1]+v[2]+v[3];
  float s2 = v[0]*v[0]+v[1]*v[1]+v[2]*v[2]+v[3]*v[3];
  block_red2(s1, s2);
  float mu = s1 * (1.f/1024.f);
  float var = s2 * (1.f/1024.f) - mu*mu;
  float rs = rsqrtf(var + 1e-5f);
#pragma unroll
  for (int e = 0; e < 4; e++){
    int col = tid*4 + e;
    out[base + col] = f2b((v[e]-mu)*rs*g[col] + be[col]);
  }
}

// ---------------------------------------------------------------- out = resid + LN(sum4(go) + xn + bias)  (fp32 out)
__global__ __launch_bounds__(256) void add_ln_k(const float* __restrict__ go,
    const u16* __restrict__ xn, const float* __restrict__ bias,
    const float* __restrict__ g, const float* __restrict__ be,
    const float* __restrict__ resid, float* __restrict__ outp)
{
  const long PS = 2097152;
  long base = (long)blockIdx.x * 1024;
  int tid = threadIdx.x;
  float v[4];
#pragma unroll
  for (int e = 0; e < 4; e++){
    int col = tid*4 + e;
    long idx = base + col;
    v[e] = go[idx] + go[idx + PS] + go[idx + 2*PS] + go[idx + 3*PS] + b2f(xn[idx]) + bias[col];
  }
  float s1 = v[0]+v[1]+v[2]+v[3];
  float s2 = v[0]*v[0]+v[1]*v[1]+v[2]*v[2]+v[3]*v[3];
  block_red2(s1, s2);
  float mu = s1 * (1.f/1024.f);
  float var = s2 * (1.f/1024.f) - mu*mu;
  float rs = rsqrtf(var + 1e-5f);
#pragma unroll
  for (int e = 0; e < 4; e++){
    int col = tid*4 + e;
    outp[base + col] = resid[base + col] + (v[e]-mu)*rs*g[col] + be[col];
  }
}

// ---------------------------------------------------------------- QQ = [q+u | shifted(q+v)]  (B,S,H,128)
__global__ __launch_bounds__(256) void build_qq(const u16* __restrict__ q, const float* __restrict__ u,
                                                const float* __restrict__ v, u16* __restrict__ QQ)
{
  int bi = blockIdx.x;
  long qrow = (long)bi * 1024;
  long obase = (long)bi * 2048;
  int n = bi + 2;
  int bp = n / 1025, ip = n % 1025;
  long qsrc = ip ? ((long)(bp*1024 + ip - 1)) * 1024 : -1;
  for (int t = threadIdx.x; t < 2048; t += 256){
    int h = t >> 7, e = t & 127;
    float val;
    if (e < 64) val = b2f(q[qrow + h*64 + e]) + u[h*64 + e];
    else {
      int d = e - 64;
      val = (qsrc < 0) ? 0.f : b2f(q[qsrc + h*64 + d]) + v[h*64 + d];
    }
    QQ[obase + t] = f2b(val);
  }
}

// ---------------------------------------------------------------- BB = [k | pos_emb]  (B,St,H,128)
__global__ __launch_bounds__(256) void build_bb(const u16* __restrict__ kv, const float* __restrict__ pe,
                                                u16* __restrict__ BB)
{
  int bj = blockIdx.x;
  int j = bj & 2047;
  long kvrow = (long)bj * 2048;
  long obase = (long)bj * 2048;
  for (int t = threadIdx.x; t < 2048; t += 256){
    int h = t >> 7, e = t & 127;
    u16 val = (e < 64) ? kv[kvrow + h*64 + e] : f2b(pe[(long)j*1024 + h*64 + (e - 64)]);
    BB[obase + t] = val;
  }
}

// ---------------------------------------------------------------- out3 = out2 + sum4(f2) + b2  (fp32 out, float4)
__global__ __launch_bounds__(256) void final_k(const float* __restrict__ out2, const float* __restrict__ f2,
                                               const float* __restrict__ b2v, float* __restrict__ outp)
{
  const long PS = 2097152;
  long i = ((long)blockIdx.x*256 + threadIdx.x) * 4;
  float4 o2 = *(const float4*)&out2[i];
  float4 a0 = *(const float4*)&f2[i];
  float4 a1 = *(const float4*)&f2[i + PS];
  float4 a2 = *(const float4*)&f2[i + 2*PS];
  float4 a3 = *(const float4*)&f2[i + 3*PS];
  float4 bb = *(const float4*)&b2v[i & 1023];
  float4 r;
  r.x = o2.x + a0.x + a1.x + a2.x + a3.x + bb.x;
  r.y = o2.y + a0.y + a1.y + a2.y + a3.y + bb.y;
  r.z = o2.z + a0.z + a1.z + a2.z + a3.z + bb.z;
  r.w = o2.w + a0.w + a1.w + a2.w + a3.w + bb.w;
  *(float4*)&outp[i] = r;
}

// ================================================================ host
extern "C" void kernel_launch(void* const* d_in, const int* in_sizes, int n_in,
                              void* d_out, int out_size, void* d_ws, size_t ws_size,
                              hipStream_t stream)
{
  (void)in_sizes; (void)n_in; (void)out_size; (void)ws_size;
  // B=2 S=1024 M=1024 St=2048 D=DI=1024 H=16 DH=64 DFF=4096 ; ALL inputs/output fp32
  const float* X    = (const float*)d_in[0];
  const float* ENC  = (const float*)d_in[1];
  const float* PE   = (const float*)d_in[2];
  const float* Uu   = (const float*)d_in[3];
  const float* Vv   = (const float*)d_in[4];
  const float* MEM  = (const float*)d_in[5];
  const float* WQM  = (const float*)d_in[7];
  const float* WKVM = (const float*)d_in[8];
  const float* FCWM = (const float*)d_in[9];
  const float* FCBM = (const float*)d_in[10];
  const float* LNMG = (const float*)d_in[11];
  const float* LNMB = (const float*)d_in[12];
  const float* WQC  = (const float*)d_in[13];
  const float* WKVC = (const float*)d_in[14];
  const float* FCWC = (const float*)d_in[15];
  const float* FCBC = (const float*)d_in[16];
  const float* LNCG = (const float*)d_in[17];
  const float* LNCB = (const float*)d_in[18];
  const float* W1   = (const float*)d_in[19];
  const float* B1   = (const float*)d_in[20];
  const float* W2   = (const float*)d_in[21];
  const float* B2   = (const float*)d_in[22];
  const float* LN1G = (const float*)d_in[23];
  const float* LN1B = (const float*)d_in[24];
  const float* LN2G = (const float*)d_in[25];
  const float* LN2B = (const float*)d_in[26];
  const float* LN3G = (const float*)d_in[27];
  const float* LN3B = (const float*)d_in[28];
  float* OUT = (float*)d_out;
  char* W = (char*)d_ws;
  const size_t MB = 1ull << 20;

  // ---- layout, peak 122 MB (same as R9)
  u16*   wT_a  = (u16*)(W + 0*MB);
  u16*   wT_b  = (u16*)(W + 2*MB);
  u16*   wT_c  = (u16*)(W + 6*MB);
  u16*   w1T   = (u16*)(W + 0*MB);
  u16*   xn1   = (u16*)(W + 8*MB);
  u16*   q     = (u16*)(W + 12*MB);
  u16*   o_b   = (u16*)(W + 12*MB);
  u16*   kv    = (u16*)(W + 16*MB);
  float* outb  = (float*)(W + 24*MB);
  u16*   QQ    = (u16*)(W + 32*MB);
  u16*   xn2   = (u16*)(W + 32*MB);
  u16*   qc    = (u16*)(W + 36*MB);
  u16*   BB    = (u16*)(W + 40*MB);
  u16*   kvc   = (u16*)(W + 40*MB);
  u16*   Vtc   = (u16*)(W + 48*MB);
  u16*   oc    = (u16*)(W + 52*MB);
  u16*   Vt    = (u16*)(W + 56*MB);
  u16*   w2T   = (u16*)(W + 56*MB);
  float* mzb   = (float*)(W + 64*MB);
  u16*   memb  = (u16*)(W + 68*MB);
  u16*   encb  = (u16*)(W + 68*MB);
  float* opart = (float*)(W + 66*MB);    // 2 partials x 8 MB (dead before ofc is written;
                                         // R18: also q/qc K-split partials — memb/encb
                                         // are consumed by the kv GEMMs FIRST)
  float* ofc   = (float*)(W + 66*MB);    // 4 partials x 8 MB
  float* f2    = (float*)(W + 66*MB);    // 4 partials x 8 MB
  u16*   h1    = (u16*)(W + 98*MB);
  float* out2b = (float*)(W + 114*MB);

  // ================= MHA (Transformer-XL relative attention) =================
  transpose_cvt_k<<<dim3(16,16),256,0,stream>>>(WQM,  wT_a, 1024,1024);
  transpose_cvt_k<<<dim3(32,16),256,0,stream>>>(WKVM, wT_b, 2048,1024);
  transpose_cvt_k<<<dim3(16,16),256,0,stream>>>(FCWM, wT_c, 1024,1024);
  cvt_k<<<2048,256,0,stream>>>(MEM, memb);
  ln_k<<<2048,256,0,stream>>>(X, LN1G, LN1B, xn1);
  // merged kv GEMM FIRST (consumes memb before q-partials overwrite [66,82)MB)
  gemm_bt<2,2,1><<<dim3(16,8,4),256,0,stream>>>(memb, xn1, wT_b, kv, nullptr, 1024, 1024,1024,2048, 2,
      1048576,0, 0,0, 4194304,2097152);
  // q GEMM: 2-way K-split (R18) — 128 blocks (0.5/CU, starved) -> 256 blocks
  gemm_bt<2,2,0><<<dim3(8,16,2),256,0,stream>>>(xn1, nullptr, wT_a, opart, nullptr, 512, 1024,1024,1024, 2,
      0,512, 0,512, 0,2097152);
  combine_o<2><<<2048,256,0,stream>>>(opart, q);
  build_qq<<<2048,256,0,stream>>>(q, Uu, Vv, QQ);
  build_bb<<<4096,256,0,stream>>>(kv, PE, BB);
  transpose_k<<<dim3(1,32,32),256,0,stream>>>(kv + 1024, Vt, 2048, 2048, 16,
      4194304,64, 2097152,131072);
  attn_passA<128,true><<<dim3(32,32),256,0,stream>>>(BB, QQ, mzb, 2048, 2048, 2048,
      4194304,128, 2097152,128, 16, 0.125f, 65536);
  attn_passB<128,true><<<dim3(16,32,2),256,0,stream>>>(BB, QQ, Vt, mzb, opart, 2048,
      2048,2048,2048,1024, 4194304,128, 2097152,128, 2097152,131072, 1048576,64, 16, 0.125f, 65536,
      8, 2097152);
  combine_o<2><<<2048,256,0,stream>>>(opart, o_b);
  gemm_bt<2,2,0><<<dim3(8,16,4),256,0,stream>>>(o_b, nullptr, wT_c, ofc, nullptr, 256, 1024,1024,1024, 4,
      0,256, 0,256, 0,2097152);
  add_ln_k<<<2048,256,0,stream>>>(ofc, xn1, FCBM, LNMG, LNMB, X, outb);

  // ================= cross attention =================
  transpose_cvt_k<<<dim3(16,16),256,0,stream>>>(WQC,  wT_a, 1024,1024);
  transpose_cvt_k<<<dim3(32,16),256,0,stream>>>(WKVC, wT_b, 2048,1024);
  transpose_cvt_k<<<dim3(16,16),256,0,stream>>>(FCWC, wT_c, 1024,1024);
  cvt_k<<<2048,256,0,stream>>>(ENC, encb);
  ln_k<<<2048,256,0,stream>>>(outb, LN2G, LN2B, xn2);
  // kvc GEMM FIRST (consumes encb before qc-partials overwrite [66,82)MB)
  gemm_bt<2,2,1><<<dim3(16,16,1),256,0,stream>>>(encb, nullptr, wT_b, kvc, nullptr, 1024, 1024,1024,2048, 1, 0,0,0,0,0,0);
  // qc GEMM: 2-way K-split (R18)
  gemm_bt<2,2,0><<<dim3(8,16,2),256,0,stream>>>(xn2, nullptr, wT_a, opart, nullptr, 512, 1024,1024,1024, 2,
      0,512, 0,512, 0,2097152);
  combine_o<2><<<2048,256,0,stream>>>(opart, qc);
  transpose_k<<<dim3(1,16,32),256,0,stream>>>(kvc + 1024, Vtc, 2048, 1024, 16,
      2097152,64, 1048576,65536);
  attn_passA<64,false><<<dim3(16,32),256,0,stream>>>(kvc, qc, mzb, 1024, 2048, 1024,
      2097152,64, 1048576,64, 16, 0.125f, 32768);
  attn_passB<64,false><<<dim3(16,32,2),256,0,stream>>>(kvc, qc, Vtc, mzb, opart, 1024,
      2048,1024,1024,1024, 2097152,64, 1048576,64, 1048576,65536, 1048576,64, 16, 0.125f, 32768,
      4, 2097152);
  combine_o<2><<<2048,256,0,stream>>>(opart, oc);
  gemm_bt<2,2,0><<<dim3(8,16,4),256,0,stream>>>(oc, nullptr, wT_c, ofc, nullptr, 256, 1024,1024,1024, 4,
      0,256, 0,256, 0,2097152);
  add_ln_k<<<2048,256,0,stream>>>(ofc, xn2, FCBC, LNCG, LNCB, outb, out2b);

  // ================= FFN =================
  transpose_cvt_k<<<dim3(64,16),256,0,stream>>>(W1, w1T, 4096,1024);
  transpose_cvt_k<<<dim3(16,64),256,0,stream>>>(W2, w2T, 1024,4096);
  ln_k<<<2048,256,0,stream>>>(out2b, LN3G, LN3B, xn2);
  gemm_bt<2,2,2><<<dim3(32,16,1),256,0,stream>>>(xn2, nullptr, w1T, h1, B1, 1024, 1024,1024,4096, 1, 0,0,0,0,0,0);
  gemm_bt<2,2,0><<<dim3(8,16,4),256,0,stream>>>(h1, nullptr, w2T, f2, nullptr, 1024, 4096,4096,1024, 4,
      0,1024, 0,1024, 0,2097152);
  final_k<<<2048,256,0,stream>>>(out2b, f2, B2, OUT);
}